// Round 8
// baseline (1196.527 us; speedup 1.0000x reference)
//
#include <hip/hip_runtime.h>
#include <math.h>

#define BB 4
#define C1 128
#define H1 128
#define W1 128
#define C2 256
#define H2 64
#define W2 64
#define LSEQ 4096
#define HID 256
#define DIN 512
#define DST 16
#define DTR 16
#define NL 4
#define NCHUNK 128
#define LCH 32

typedef unsigned short u16;
using short8 = __attribute__((ext_vector_type(8))) short;
using f32x4  = __attribute__((ext_vector_type(4))) float;
using f32x2  = __attribute__((ext_vector_type(2))) float;

static __device__ __forceinline__ float dsilu(float x){
    return x / (1.0f + __expf(-x));
}
static __device__ __forceinline__ u16 f2bf(float f){
    unsigned u = __float_as_uint(f);
    u += 0x7FFF + ((u >> 16) & 1);
    return (u16)(u >> 16);
}
static __device__ __forceinline__ float bf2f(u16 v){
    return __uint_as_float(((unsigned)v) << 16);
}

#define GLL16(g, l) __builtin_amdgcn_global_load_lds( \
    (const __attribute__((address_space(1))) void*)(g), \
    (__attribute__((address_space(3))) void*)(l), 16, 0, 0)

// ---------------- weight prep ----------------
__global__ void f2bf_kernel(const float* __restrict__ src, u16* __restrict__ dst){
    int idx = blockIdx.x * 256 + threadIdx.x;
    dst[idx] = f2bf(src[idx]);
}
__global__ void xpw_pad_kernel(const float* __restrict__ src, u16* __restrict__ dst){
    int idx = blockIdx.x * 256 + threadIdx.x;   // 4*128*512
    int k = idx & 511, row = (idx >> 9) & 127, layer = idx >> 16;
    dst[idx] = (row < 48) ? f2bf(src[((long)layer*48 + row)*512 + k]) : 0;
}
// conv2_w [co][ci][kh][kw] -> w2 [co][p=kh*3+kw][ci] bf16
__global__ void c2w_prep_kernel(const float* __restrict__ src, u16* __restrict__ dst){
    int idx = blockIdx.x * 256 + threadIdx.x;   // 256*9*128 = 294912
    int ci = idx & 127, p = (idx >> 7) % 9, co = idx / (9*128);
    int kh = p / 3, kw = p - 3*kh;
    dst[idx] = f2bf(src[((co*128 + ci)*3 + kh)*3 + kw]);
}
__global__ void xt_zero_kernel(unsigned* __restrict__ xt){
    xt[blockIdx.x * 256 + threadIdx.x] = 0;     // 4,326,400 uints
}

// ---------------- conv1 via LDS row staging ----------------
__global__ __launch_bounds__(256) void conv1_kernel(
        const float* __restrict__ x, const float* __restrict__ w,
        const float* __restrict__ bias, float* __restrict__ y){
    __shared__ float xs[9][260];
    int oh = blockIdx.x, b = blockIdx.y;
    int tid = threadIdx.x;
    #pragma unroll
    for(int r = 0; r < 9; ++r){
        int ci = r / 3, kh = r - 3*ci;
        int ih = 2*oh - 1 + kh;
        float v = 0.f;
        if(ih >= 0) v = x[((b*3 + ci)*256 + ih)*256 + tid];
        xs[r][tid + 1] = v;
        if(tid == 0) xs[r][0] = 0.f;
    }
    __syncthreads();
    int co = tid >> 1, h = tid & 1;
    float wr[27];
    #pragma unroll
    for(int j = 0; j < 27; ++j) wr[j] = w[co*27 + j];
    float bz = bias[co];
    long obase = ((long)((b*128 + co)*128 + oh))*128 + h*64;
    #pragma unroll 4
    for(int i = 0; i < 64; ++i){
        int iw0 = 2*(h*64 + i);
        float acc = bz;
        #pragma unroll
        for(int r = 0; r < 9; ++r){
            acc = fmaf(xs[r][iw0+0], wr[r*3+0], acc);
            acc = fmaf(xs[r][iw0+1], wr[r*3+1], acc);
            acc = fmaf(xs[r][iw0+2], wr[r*3+2], acc);
        }
        y[obase + i] = acc;
    }
}

// ---------------- GN stats ----------------
__global__ void zero_stats_kernel(float* __restrict__ stats){
    stats[threadIdx.x] = 0.0f;   // 64 threads
}

__global__ void gn_stats_kernel(const float* __restrict__ x, float* __restrict__ stats,
                                int elems_per_group){
    const int EPB = 16384;
    long base = (long)blockIdx.x * EPB;
    int g = (int)(base / elems_per_group);
    float s = 0.f, ss = 0.f;
    for(int j = threadIdx.x; j < EPB; j += 256){
        float v = x[base + j];
        s += v; ss += v*v;
    }
    #pragma unroll
    for(int off = 32; off; off >>= 1){
        s  += __shfl_down(s,  off);
        ss += __shfl_down(ss, off);
    }
    __shared__ float ls[4], lss[4];
    int wid = threadIdx.x >> 6, lane = threadIdx.x & 63;
    if(lane == 0){ ls[wid] = s; lss[wid] = ss; }
    __syncthreads();
    if(threadIdx.x == 0){
        atomicAdd(&stats[g],      ls[0]+ls[1]+ls[2]+ls[3]);
        atomicAdd(&stats[32+g], lss[0]+lss[1]+lss[2]+lss[3]);
    }
}

// ---------------- GN1 apply + SiLU + NCHW -> padded channels-last bf16 ----------------
__global__ void gn1_transform_kernel(const float* __restrict__ y1, const float* __restrict__ stats,
                                     const float* __restrict__ w, const float* __restrict__ bias,
                                     u16* __restrict__ xt){
    __shared__ float tile[32][33];
    int b = blockIdx.z >> 7, ih = blockIdx.z & 127;
    int c0 = blockIdx.y * 32, w0 = blockIdx.x * 32;
    int tx = threadIdx.x, ty = threadIdx.y;   // 32 x 8
    const float cnt = 16.f * 128.f * 128.f;
    #pragma unroll
    for(int i = 0; i < 4; ++i){
        int ci = c0 + ty + i*8;
        int g = b*8 + (ci >> 4);
        float mean = stats[g] / cnt;
        float var  = stats[32+g] / cnt - mean*mean;
        float rstd = rsqrtf(var + 1e-5f);
        float v = y1[(((long)(b*C1 + ci))*H1 + ih)*W1 + w0 + tx];
        tile[ty + i*8][tx] = dsilu((v - mean) * rstd * w[ci] + bias[ci]);
    }
    __syncthreads();
    #pragma unroll
    for(int i = 0; i < 4; ++i){
        int iwl = ty + i*8;
        xt[((long)(b*130 + ih + 1)*130 + (w0 + iwl + 1))*128 + c0 + tx] = f2bf(tile[tx][iwl]);
    }
}

// ---------------- conv2 as bf16 MFMA implicit GEMM ----------------
__global__ __launch_bounds__(256) void conv2gemm_bf16_kernel(
        const u16* __restrict__ xt, const u16* __restrict__ w2,
        const float* __restrict__ bias, float* __restrict__ y2t){
    __shared__ u16 Asm[128*32];
    __shared__ u16 Bsm[128*32];
    int m0 = blockIdx.x * 128, n0 = blockIdx.y * 128;
    int tid = threadIdx.x;
    long abase[2]; const u16* bbase[2];
    #pragma unroll
    for(int it = 0; it < 2; ++it){
        int c = it*256 + tid;
        int r = c >> 2, q = (c & 3) * 8;
        int m = m0 + r;
        int b = m >> 12, oh = (m >> 6) & 63, ow = m & 63;
        abase[it] = ((long)(b*130 + 2*oh)*130 + 2*ow)*128 + q;
        bbase[it] = w2 + (long)(n0 + r)*1152 + q;
    }
    int wave = tid >> 6, lane = tid & 63;
    int wr = wave >> 1, wc = wave & 1;
    int lm = lane & 15, lq = lane >> 4;
    f32x4 acc[4][4] = {};
    #pragma unroll 1
    for(int p = 0; p < 9; ++p){
        int kh = p / 3, kw = p - 3*kh;
        int aoff = (kh*130 + kw)*128;
        #pragma unroll 1
        for(int ci0 = 0; ci0 < 128; ci0 += 32){
            #pragma unroll
            for(int it = 0; it < 2; ++it){
                int c = it*256 + tid;
                GLL16(xt + abase[it] + aoff + ci0, &Asm[c*8]);
                GLL16(bbase[it] + p*128 + ci0, &Bsm[c*8]);
            }
            __syncthreads();
            short8 af[4], bf[4];
            #pragma unroll
            for(int i = 0; i < 4; ++i){
                af[i] = *(const short8*)&Asm[(wr*64 + i*16 + lm)*32 + lq*8];
                bf[i] = *(const short8*)&Bsm[(wc*64 + i*16 + lm)*32 + lq*8];
            }
            #pragma unroll
            for(int i = 0; i < 4; ++i)
                #pragma unroll
                for(int j = 0; j < 4; ++j)
                    acc[i][j] = __builtin_amdgcn_mfma_f32_16x16x32_bf16(af[i], bf[j], acc[i][j], 0, 0, 0);
            __syncthreads();
        }
    }
    #pragma unroll
    for(int i = 0; i < 4; ++i){
        long row = m0 + wr*64 + i*16 + lq*4;
        #pragma unroll
        for(int j = 0; j < 4; ++j){
            int col = n0 + wc*64 + j*16 + lm;
            float bz = bias[col];
            #pragma unroll
            for(int r = 0; r < 4; ++r)
                y2t[(row + r)*256L + col] = acc[i][j][r] + bz;
        }
    }
}

// ---------------- GN2 stats over [m][c] ----------------
__global__ void gn2t_stats_kernel(const float* __restrict__ y2t, float* __restrict__ stats){
    int b = blockIdx.y;
    long row0 = (long)b*LSEQ + blockIdx.x*64;
    int c = threadIdx.x;
    float s = 0.f, ss = 0.f;
    for(int r = 0; r < 64; ++r){
        float v = y2t[(row0 + r)*C2 + c];
        s += v; ss += v*v;
    }
    #pragma unroll
    for(int off = 16; off; off >>= 1){
        s  += __shfl_down(s,  off);
        ss += __shfl_down(ss, off);
    }
    if((c & 31) == 0){
        int g = b*8 + (c >> 5);
        atomicAdd(&stats[g], s);
        atomicAdd(&stats[32+g], ss);
    }
}

// ---------------- GN2 apply + SiLU -> s, fused LayerNorm(layer 0) -> xln_bf ----------------
__global__ void gn2t_apply_ln_kernel(const float* __restrict__ y2t, const float* __restrict__ stats,
                                     const float* __restrict__ gw, const float* __restrict__ gb,
                                     const float* __restrict__ lw, const float* __restrict__ lb,
                                     float* __restrict__ s, u16* __restrict__ xln){
    long row = blockIdx.x;                        // 16384 rows
    int c = threadIdx.x;                          // 256
    int b = (int)(row >> 12);
    int g = b*8 + (c >> 5);
    const float cnt = 32.f * (float)LSEQ;
    float mean = stats[g] / cnt;
    float var  = stats[32+g] / cnt - mean*mean;
    float rstd = rsqrtf(var + 1e-5f);
    float v = dsilu((y2t[row*HID + c] - mean) * rstd * gw[c] + gb[c]);
    s[row*HID + c] = v;
    // row LayerNorm
    float sm = v, sq = v*v;
    #pragma unroll
    for(int off = 32; off; off >>= 1){
        sm += __shfl_down(sm, off);
        sq += __shfl_down(sq, off);
    }
    __shared__ float pa[4], pb[4], res[2];
    int wid = c >> 6, lane = c & 63;
    if(lane == 0){ pa[wid] = sm; pb[wid] = sq; }
    __syncthreads();
    if(c == 0){
        float t  = pa[0]+pa[1]+pa[2]+pa[3];
        float tt = pb[0]+pb[1]+pb[2]+pb[3];
        float m2 = t / 256.f;
        float v2 = tt / 256.f - m2*m2;
        res[0] = m2; res[1] = rsqrtf(v2 + 1e-5f);
    }
    __syncthreads();
    xln[row*HID + c] = f2bf((v - res[0]) * res[1] * lw[c] + lb[c]);
}

// ---------------- bf16 MFMA GEMM: C[M,N] = A[M,K] * B[N,K]^T ----------------
// mode 0: fp32 store, 2: bf16 store
__global__ __launch_bounds__(256) void gemm_bf16_kernel(
        const u16* __restrict__ A, const u16* __restrict__ B, void* __restrict__ Cv,
        int K, int Nact, int ldc, int mode){
    __shared__ u16 Asm[128*32];
    __shared__ u16 Bsm[128*32];
    int m0 = blockIdx.x * 128, n0 = blockIdx.y * 128;
    int tid = threadIdx.x;
    int wave = tid >> 6, lane = tid & 63;
    int wr = wave >> 1, wc = wave & 1;
    int lm = lane & 15, lq = lane >> 4;
    f32x4 acc[4][4] = {};
    for(int k0 = 0; k0 < K; k0 += 32){
        #pragma unroll
        for(int it = 0; it < 2; ++it){
            int c = it*256 + tid;
            int row = c >> 2, kq = (c & 3) * 8;
            GLL16(A + (long)(m0 + row)*K + k0 + kq, &Asm[c*8]);
            GLL16(B + (long)(n0 + row)*K + k0 + kq, &Bsm[c*8]);
        }
        __syncthreads();
        short8 af[4], bf[4];
        #pragma unroll
        for(int i = 0; i < 4; ++i){
            af[i] = *(const short8*)&Asm[(wr*64 + i*16 + lm)*32 + lq*8];
            bf[i] = *(const short8*)&Bsm[(wc*64 + i*16 + lm)*32 + lq*8];
        }
        #pragma unroll
        for(int i = 0; i < 4; ++i)
            #pragma unroll
            for(int j = 0; j < 4; ++j)
                acc[i][j] = __builtin_amdgcn_mfma_f32_16x16x32_bf16(af[i], bf[j], acc[i][j], 0, 0, 0);
        __syncthreads();
    }
    #pragma unroll
    for(int i = 0; i < 4; ++i){
        long row = m0 + wr*64 + i*16 + lq*4;
        #pragma unroll
        for(int j = 0; j < 4; ++j){
            int col = n0 + wc*64 + j*16 + lm;
            if(col < Nact){
                #pragma unroll
                for(int r = 0; r < 4; ++r){
                    long idx = (row + r)*(long)ldc + col;
                    if(mode == 2) ((u16*)Cv)[idx] = f2bf(acc[i][j][r]);
                    else          ((float*)Cv)[idx] = acc[i][j][r];
                }
            }
        }
    }
}

// ---------------- out_proj + residual + LayerNorm fused ----------------
__global__ __launch_bounds__(256) void gemm_out_ln_kernel(
        const u16* __restrict__ A, const u16* __restrict__ B,
        float* __restrict__ s, u16* __restrict__ xln,
        const float* __restrict__ lw, const float* __restrict__ lb){
    __shared__ u16 Asm[64*32];    // 4 KB
    __shared__ u16 Bsm[256*32];   // 16 KB
    int m0 = blockIdx.x * 64;
    int tid = threadIdx.x;
    int w = tid >> 6, lane = tid & 63;
    int lm = lane & 15, lq = lane >> 4;
    f32x4 acc[16] = {};
    for(int k0 = 0; k0 < 512; k0 += 32){
        {
            int row = tid >> 2, kq = (tid & 3) * 8;
            GLL16(A + (long)(m0 + row)*512 + k0 + kq, &Asm[tid*8]);
        }
        #pragma unroll
        for(int it = 0; it < 4; ++it){
            int c = it*256 + tid;
            int row = c >> 2, kq = (c & 3) * 8;
            GLL16(B + (long)row*512 + k0 + kq, &Bsm[c*8]);
        }
        __syncthreads();
        short8 af = *(const short8*)&Asm[(w*16 + lm)*32 + lq*8];
        #pragma unroll
        for(int j = 0; j < 16; ++j){
            short8 bf = *(const short8*)&Bsm[(j*16 + lm)*32 + lq*8];
            acc[j] = __builtin_amdgcn_mfma_f32_16x16x32_bf16(af, bf, acc[j], 0, 0, 0);
        }
        __syncthreads();
    }
    int row0 = m0 + w*16 + lq*4;
    float psum[4] = {0.f,0.f,0.f,0.f}, psq[4] = {0.f,0.f,0.f,0.f};
    #pragma unroll
    for(int j = 0; j < 16; ++j){
        int col = j*16 + lm;
        #pragma unroll
        for(int r = 0; r < 4; ++r){
            long idx = (long)(row0 + r)*HID + col;
            float v = s[idx] + acc[j][r];
            acc[j][r] = v;
            s[idx] = v;
            psum[r] += v; psq[r] += v*v;
        }
    }
    #pragma unroll
    for(int mask = 1; mask <= 8; mask <<= 1){
        #pragma unroll
        for(int r = 0; r < 4; ++r){
            psum[r] += __shfl_xor(psum[r], mask);
            psq[r]  += __shfl_xor(psq[r],  mask);
        }
    }
    float mean[4], rstd[4];
    #pragma unroll
    for(int r = 0; r < 4; ++r){
        mean[r] = psum[r] * (1.f/256.f);
        float var = psq[r] * (1.f/256.f) - mean[r]*mean[r];
        rstd[r] = rsqrtf(var + 1e-5f);
    }
    #pragma unroll
    for(int j = 0; j < 16; ++j){
        int col = j*16 + lm;
        float wv = lw[col], bv = lb[col];
        #pragma unroll
        for(int r = 0; r < 4; ++r){
            long idx = (long)(row0 + r)*HID + col;
            xln[idx] = f2bf((acc[j][r] - mean[r]) * rstd[r] * wv + bv);
        }
    }
}

// ---------------- depthwise causal conv1d (k=4) + SiLU; bf16 in, bf16 out ----------------
__global__ void conv1d_silu_kernel(const u16* __restrict__ xz, const float* __restrict__ w,
                                   const float* __restrict__ bias, u16* __restrict__ xcv){
    int idx = blockIdx.x * 256 + threadIdx.x;    // 8388608
    int d = idx & 511, l = (idx >> 9) & 4095;
    const float* wp = w + d*4;
    float acc = bias[d];
    const u16* xp = xz + ((long)(idx >> 9))*(2*DIN) + d;
    #pragma unroll
    for(int j = 0; j < 4; ++j){
        int t = l - 3 + j;
        if(t >= 0) acc = fmaf(bf2f(xp[(long)(j-3)*(2*DIN)]), wp[j], acc);
    }
    xcv[idx] = f2bf(dsilu(acc));
}

// ---------------- scan phase 1: fused dt_proj+softplus, stores dv; per-chunk (prod a, h_end) ----------------
__global__ __launch_bounds__(256) void scan1_kernel(
        const u16* __restrict__ xcvb, const float* __restrict__ xdbl,
        const float* __restrict__ Alog, const float* __restrict__ dpw,
        const float* __restrict__ dpb,
        float* __restrict__ aprod, float* __restrict__ hend,
        u16* __restrict__ dvout){
    int d = blockIdx.y * 256 + threadIdx.x;
    int c = blockIdx.x;
    int b = blockIdx.z;
    __shared__ float bm[LCH][16], dtl[LCH][16];
    {
        int t = threadIdx.x >> 4, n = threadIdx.x & 15;
        #pragma unroll
        for(int it = 0; it < 2; ++it){
            long p = ((long)(b*LSEQ + c*LCH + t + it*16))*48;
            dtl[t + it*16][n] = xdbl[p + n];
            bm [t + it*16][n] = xdbl[p + 16 + n];
        }
    }
    __syncthreads();
    float An[16], dw[16];
    #pragma unroll
    for(int n = 0; n < 16; ++n){
        An[n] = -__expf(Alog[d*16 + n]);
        dw[n] = dpw[d*16 + n];
    }
    float dpbv = dpb[d];
    float An0 = An[0];
    bool structural = true;
    #pragma unroll
    for(int n = 0; n < 16; ++n)
        structural = structural && (fabsf(An[n] - (float)(n+1)*An0) <= 1e-3f*(float)(n+1));
    long base = ((long)(b*LSEQ + c*LCH))*DIN + d;
    long ob = (((long)(b*NCHUNK + c))*DIN + d)*16;
    if(structural){
        f32x2 h2[8];
        #pragma unroll
        for(int i = 0; i < 8; ++i) h2[i] = (f32x2){0.f, 0.f};
        float sumdv = 0.f;
        float xv_n = bf2f(xcvb[base]);
        for(int t = 0; t < LCH; ++t){
            float xv = xv_n;
            if(t + 1 < LCH) xv_n = bf2f(xcvb[base + (long)(t+1)*DIN]);
            float acc = dpbv;
            #pragma unroll
            for(int r4 = 0; r4 < 4; ++r4){
                float4 d4 = *(const float4*)&dtl[t][r4*4];
                acc = fmaf(d4.x, dw[r4*4+0], acc);
                acc = fmaf(d4.y, dw[r4*4+1], acc);
                acc = fmaf(d4.z, dw[r4*4+2], acc);
                acc = fmaf(d4.w, dw[r4*4+3], acc);
            }
            float dv = (acc > 20.f) ? acc : log1pf(__expf(acc));
            dvout[base + (long)t*DIN] = f2bf(dv);
            dv = bf2f(f2bf(dv));       // match scan3's rounded view for consistency
            sumdv += dv;
            float db = dv * xv;
            float r1 = __expf(dv * An0);
            float r2 = r1 * r1;
            f32x2 rr = {r2, r2};
            f32x2 e2[8];
            e2[0] = (f32x2){r1, r2};
            #pragma unroll
            for(int i = 1; i < 8; ++i) e2[i] = e2[i-1] * rr;
            f32x2 db2 = {db, db};
            const f32x2* b2 = (const f32x2*)&bm[t][0];
            #pragma unroll
            for(int i = 0; i < 8; ++i) h2[i] = e2[i]*h2[i] + db2*b2[i];
        }
        float R = __expf(An0 * sumdv);
        float Rp = R;
        const float* hp = (const float*)h2;
        #pragma unroll
        for(int n = 0; n < 16; ++n){
            aprod[ob+n] = Rp; Rp *= R;
            hend[ob+n] = hp[n];
        }
    } else {
        float h[16], ap[16];
        #pragma unroll
        for(int n = 0; n < 16; ++n){ h[n] = 0.f; ap[n] = 1.f; }
        for(int t = 0; t < LCH; ++t){
            float acc = dpbv;
            #pragma unroll
            for(int r = 0; r < 16; ++r) acc = fmaf(dtl[t][r], dw[r], acc);
            float dv = (acc > 20.f) ? acc : log1pf(__expf(acc));
            dvout[base + (long)t*DIN] = f2bf(dv);
            dv = bf2f(f2bf(dv));
            float db = dv * bf2f(xcvb[base + (long)t*DIN]);
            #pragma unroll
            for(int n = 0; n < 16; ++n){
                float e = __expf(dv * An[n]);
                ap[n] *= e;
                h[n] = fmaf(e, h[n], db * bm[t][n]);
            }
        }
        #pragma unroll
        for(int n = 0; n < 16; ++n){ aprod[ob+n] = ap[n]; hend[ob+n] = h[n]; }
    }
}

// ---------------- scan phase 2: sequential combine, 8-deep load batching ----------------
__global__ void scan2_kernel(const float* __restrict__ aprod, const float* __restrict__ hend,
                             float* __restrict__ hinit){
    int idx = blockIdx.x * 256 + threadIdx.x;    // 32768
    int n = idx & 15, d = (idx >> 4) & 511, b = idx >> 13;
    const long stride = (long)DIN * 16;
    long p0 = (((long)(b*NCHUNK))*DIN + d)*16 + n;
    float h = 0.f;
    for(int c = 0; c < NCHUNK; c += 8){
        float a[8], e[8];
        #pragma unroll
        for(int j = 0; j < 8; ++j){
            long p = p0 + (long)(c + j)*stride;
            a[j] = aprod[p]; e[j] = hend[p];
        }
        #pragma unroll
        for(int j = 0; j < 8; ++j){
            hinit[p0 + (long)(c + j)*stride] = h;
            h = fmaf(a[j], h, e[j]);
        }
    }
}

// ---------------- scan phase 3: reads dv; replay + epilogue -> bf16 y ----------------
__global__ __launch_bounds__(256) void scan3_kernel(
        const u16* __restrict__ xcvb, const u16* __restrict__ dvin,
        const float* __restrict__ xdbl, const float* __restrict__ Alog,
        const float* __restrict__ hinit, const float* __restrict__ Dp,
        const u16* __restrict__ xz, u16* __restrict__ yout){
    int d = blockIdx.y * 256 + threadIdx.x;
    int c = blockIdx.x;
    int b = blockIdx.z;
    __shared__ float bm[LCH][16], cm[LCH][16];
    {
        int t = threadIdx.x >> 4, n = threadIdx.x & 15;
        #pragma unroll
        for(int it = 0; it < 2; ++it){
            long p = ((long)(b*LSEQ + c*LCH + t + it*16))*48;
            bm[t + it*16][n] = xdbl[p + 16 + n];
            cm[t + it*16][n] = xdbl[p + 32 + n];
        }
    }
    __syncthreads();
    float An[16];
    long hb = (((long)(b*NCHUNK + c))*DIN + d)*16;
    #pragma unroll
    for(int n = 0; n < 16; ++n)
        An[n] = -__expf(Alog[d*16 + n]);
    float An0 = An[0];
    bool structural = true;
    #pragma unroll
    for(int n = 0; n < 16; ++n)
        structural = structural && (fabsf(An[n] - (float)(n+1)*An0) <= 1e-3f*(float)(n+1));
    float Dv = Dp[d];
    long base  = ((long)(b*LSEQ + c*LCH))*DIN + d;
    long zbase = ((long)(b*LSEQ + c*LCH))*(2*DIN) + DIN + d;
    if(structural){
        f32x2 h2[8];
        {
            const f32x2* hi = (const f32x2*)&hinit[hb];
            #pragma unroll
            for(int i = 0; i < 8; ++i) h2[i] = hi[i];
        }
        float xv_n = bf2f(xcvb[base]);
        float z_n  = bf2f(xz[zbase]);
        float dv_n = bf2f(dvin[base]);
        for(int t = 0; t < LCH; ++t){
            float xv = xv_n, z = z_n, dv = dv_n;
            if(t + 1 < LCH){
                xv_n = bf2f(xcvb[base + (long)(t+1)*DIN]);
                z_n  = bf2f(xz[zbase + (long)(t+1)*(2*DIN)]);
                dv_n = bf2f(dvin[base + (long)(t+1)*DIN]);
            }
            float db = dv * xv;
            float r1 = __expf(dv * An0);
            float r2 = r1 * r1;
            f32x2 rr = {r2, r2};
            f32x2 e2[8];
            e2[0] = (f32x2){r1, r2};
            #pragma unroll
            for(int i = 1; i < 8; ++i) e2[i] = e2[i-1] * rr;
            f32x2 db2 = {db, db};
            const f32x2* b2 = (const f32x2*)&bm[t][0];
            const f32x2* c2 = (const f32x2*)&cm[t][0];
            f32x2 y2 = {0.f, 0.f};
            #pragma unroll
            for(int i = 0; i < 8; ++i){
                h2[i] = e2[i]*h2[i] + db2*b2[i];
                y2 = y2 + h2[i]*c2[i];
            }
            float y = y2[0] + y2[1];
            y = fmaf(xv, Dv, y);
            yout[base + (long)t*DIN] = f2bf(y * dsilu(z));
        }
    } else {
        float h[16];
        #pragma unroll
        for(int n = 0; n < 16; ++n) h[n] = hinit[hb + n];
        for(int t = 0; t < LCH; ++t){
            float dv = bf2f(dvin[base + (long)t*DIN]);
            float xv = bf2f(xcvb[base + (long)t*DIN]);
            float db = dv * xv;
            float y = 0.f;
            #pragma unroll
            for(int n = 0; n < 16; ++n){
                float e = __expf(dv * An[n]);
                h[n] = fmaf(e, h[n], db * bm[t][n]);
                y = fmaf(h[n], cm[t][n], y);
            }
            y = fmaf(xv, Dv, y);
            float z = bf2f(xz[zbase + (long)t*(2*DIN)]);
            yout[base + (long)t*DIN] = f2bf(y * dsilu(z));
        }
    }
}

// ---------------- final copy ----------------
__global__ void copyout_kernel(const float* __restrict__ s, float* __restrict__ out, int out_size){
    int idx = blockIdx.x * 256 + threadIdx.x;
    if(idx >= out_size) return;
    out[idx] = (idx < BB*LSEQ*HID) ? s[idx] : 64.0f;
}

extern "C" void kernel_launch(void* const* d_in, const int* in_sizes, int n_in,
                              void* d_out, int out_size, void* d_ws, size_t ws_size,
                              hipStream_t stream){
    const float* x        = (const float*)d_in[0];
    const float* conv1_w  = (const float*)d_in[1];
    const float* conv1_b  = (const float*)d_in[2];
    const float* gn1_w    = (const float*)d_in[3];
    const float* gn1_b    = (const float*)d_in[4];
    const float* conv2_w  = (const float*)d_in[5];
    const float* conv2_b  = (const float*)d_in[6];
    const float* gn2_w    = (const float*)d_in[7];
    const float* gn2_b    = (const float*)d_in[8];
    const float* ln_w     = (const float*)d_in[9];
    const float* ln_b     = (const float*)d_in[10];
    const float* in_proj  = (const float*)d_in[11];
    const float* c1d_w    = (const float*)d_in[12];
    const float* c1d_b    = (const float*)d_in[13];
    const float* x_proj   = (const float*)d_in[14];
    const float* dt_w     = (const float*)d_in[15];
    const float* dt_b     = (const float*)d_in[16];
    const float* A_log    = (const float*)d_in[17];
    const float* Dvec     = (const float*)d_in[18];
    const float* out_proj = (const float*)d_in[19];

    float* ws = (float*)d_ws;
    float* s      = ws;                       // 4,194,304 f
    u16*   xz_bf  = (u16*)(ws + 4194304);     // 16,777,216 u16 (8,388,608 f)
    float* y1     = ws + 4194304;             // alias: y1 fp32 (stem only)
    u16*   xt     = (u16*)(ws + 12582912);    // 8,652,800 u16 (4,326,400 f)
    u16*   xcv_bf = (u16*)(ws + 16909312);    // 8,388,608 u16 (4,194,304 f)
    float* y2t    = ws + 16909312;            // alias: y2t fp32 (stem only)
    u16*   xln_bf = (u16*)(ws + 21103616);    // 4,194,304 u16 (2,097,152 f)
    float* xdbl   = ws + 23200768;            // 786,432 f
    float* aprod  = ws + 23987200;            // 4,194,304 f
    float* hendb  = ws + 28181504;            // 4,194,304 f
    u16*   y_bf   = (u16*)aprod;              // alias: 8,388,608 u16 fits in aprod
    float* hinit  = ws + 32375808;            // 4,194,304 f
    float* stats  = ws + 36570112;            // 64 f
    u16*   ipw_bf = (u16*)(ws + 36570176);    // 1,048,576 u16 (524,288 f)
    u16*   xpw_bf = ipw_bf + 1048576;         //   262,144 u16 (131,072 f)
    u16*   opw_bf = xpw_bf + 262144;          //   524,288 u16 (262,144 f)
    u16*   c2w_bf = opw_bf + 524288;          //   294,912 u16 (147,456 f)
    u16*   dv_bf  = (u16*)(ws + 37635200);    // 8,388,608 u16 (4,194,304 f) -> end 41,829,504 f

    // ---- weight prep ----
    f2bf_kernel<<<4096, 256, 0, stream>>>(in_proj, ipw_bf);
    f2bf_kernel<<<2048, 256, 0, stream>>>(out_proj, opw_bf);
    xpw_pad_kernel<<<1024, 256, 0, stream>>>(x_proj, xpw_bf);
    c2w_prep_kernel<<<1152, 256, 0, stream>>>(conv2_w, c2w_bf);

    // ---- stem ----
    conv1_kernel<<<dim3(128,4), 256, 0, stream>>>(x, conv1_w, conv1_b, y1);
    zero_stats_kernel<<<1, 64, 0, stream>>>(stats);
    gn_stats_kernel<<<512, 256, 0, stream>>>(y1, stats, 16*H1*W1);
    xt_zero_kernel<<<16900, 256, 0, stream>>>((unsigned*)xt);
    gn1_transform_kernel<<<dim3(4,4,512), dim3(32,8), 0, stream>>>(y1, stats, gn1_w, gn1_b, xt);
    conv2gemm_bf16_kernel<<<dim3(128,2), 256, 0, stream>>>(xt, c2w_bf, conv2_b, y2t);
    zero_stats_kernel<<<1, 64, 0, stream>>>(stats);
    gn2t_stats_kernel<<<dim3(64,4), 256, 0, stream>>>(y2t, stats);
    gn2t_apply_ln_kernel<<<16384, 256, 0, stream>>>(y2t, stats, gn2_w, gn2_b,
                                                    ln_w, ln_b, s, xln_bf);

    // ---- 4 mamba layers ----
    for(int layer = 0; layer < NL; ++layer){
        const float* cw  = c1d_w + (long)layer*DIN*4;
        const float* cb  = c1d_b + (long)layer*DIN;
        const float* dpw = dt_w  + (long)layer*DIN*DTR;
        const float* dpb = dt_b  + (long)layer*DIN;
        const float* Al  = A_log + (long)layer*DIN*DST;
        const float* Dl  = Dvec  + (long)layer*DIN;
        int lnext = (layer + 1) & 3;   // ln params for the NEXT layer's input

        gemm_bf16_kernel<<<dim3(128,8), 256, 0, stream>>>(
            xln_bf, ipw_bf + (long)layer*1024*256, xz_bf, HID, 2*DIN, 2*DIN, 2);
        conv1d_silu_kernel<<<32768, 256, 0, stream>>>(xz_bf, cw, cb, xcv_bf);
        gemm_bf16_kernel<<<dim3(128,1), 256, 0, stream>>>(
            xcv_bf, xpw_bf + (long)layer*128*512, xdbl, DIN, 48, 48, 0);
        scan1_kernel<<<dim3(NCHUNK,2,BB), 256, 0, stream>>>(
            xcv_bf, xdbl, Al, dpw, dpb, aprod, hendb, dv_bf);
        scan2_kernel<<<128, 256, 0, stream>>>(aprod, hendb, hinit);
        scan3_kernel<<<dim3(NCHUNK,2,BB), 256, 0, stream>>>(
            xcv_bf, dv_bf, xdbl, Al, hinit, Dl, xz_bf, y_bf);
        gemm_out_ln_kernel<<<256, 256, 0, stream>>>(
            y_bf, opw_bf + (long)layer*256*512, s, xln_bf,
            ln_w + lnext*HID, ln_b + lnext*HID);
    }

    copyout_kernel<<<(out_size + 255)/256, 256, 0, stream>>>(s, (float*)d_out, out_size);
}

// Round 9
// 1066.405 us; speedup vs baseline: 1.1220x; 1.1220x over previous
//
#include <hip/hip_runtime.h>
#include <math.h>

#define BB 4
#define C1 128
#define H1 128
#define W1 128
#define C2 256
#define H2 64
#define W2 64
#define LSEQ 4096
#define HID 256
#define DIN 512
#define DST 16
#define DTR 16
#define NL 4
#define NCHUNK 128
#define LCH 32

typedef unsigned short u16;
using short8 = __attribute__((ext_vector_type(8))) short;
using f32x4  = __attribute__((ext_vector_type(4))) float;
using f32x2  = __attribute__((ext_vector_type(2))) float;

static __device__ __forceinline__ float dsilu(float x){
    return x / (1.0f + __expf(-x));
}
static __device__ __forceinline__ u16 f2bf(float f){
    unsigned u = __float_as_uint(f);
    u += 0x7FFF + ((u >> 16) & 1);
    return (u16)(u >> 16);
}
static __device__ __forceinline__ float bf2f(u16 v){
    return __uint_as_float(((unsigned)v) << 16);
}

#define GLL16(g, l) __builtin_amdgcn_global_load_lds( \
    (const __attribute__((address_space(1))) void*)(g), \
    (__attribute__((address_space(3))) void*)(l), 16, 0, 0)

// ---------------- weight prep ----------------
__global__ void f2bf_kernel(const float* __restrict__ src, u16* __restrict__ dst){
    int idx = blockIdx.x * 256 + threadIdx.x;
    dst[idx] = f2bf(src[idx]);
}
__global__ void xpw_pad_kernel(const float* __restrict__ src, u16* __restrict__ dst){
    int idx = blockIdx.x * 256 + threadIdx.x;   // 4*128*512
    int k = idx & 511, row = (idx >> 9) & 127, layer = idx >> 16;
    dst[idx] = (row < 48) ? f2bf(src[((long)layer*48 + row)*512 + k]) : 0;
}
// conv2_w [co][ci][kh][kw] -> w2 [co][p=kh*3+kw][ci] bf16
__global__ void c2w_prep_kernel(const float* __restrict__ src, u16* __restrict__ dst){
    int idx = blockIdx.x * 256 + threadIdx.x;   // 256*9*128 = 294912
    int ci = idx & 127, p = (idx >> 7) % 9, co = idx / (9*128);
    int kh = p / 3, kw = p - 3*kh;
    dst[idx] = f2bf(src[((co*128 + ci)*3 + kh)*3 + kw]);
}
__global__ void xt_zero_kernel(unsigned* __restrict__ xt){
    xt[blockIdx.x * 256 + threadIdx.x] = 0;     // 4,326,400 uints
}

// ---------------- conv1 via LDS row staging ----------------
__global__ __launch_bounds__(256) void conv1_kernel(
        const float* __restrict__ x, const float* __restrict__ w,
        const float* __restrict__ bias, float* __restrict__ y){
    __shared__ float xs[9][260];
    int oh = blockIdx.x, b = blockIdx.y;
    int tid = threadIdx.x;
    #pragma unroll
    for(int r = 0; r < 9; ++r){
        int ci = r / 3, kh = r - 3*ci;
        int ih = 2*oh - 1 + kh;
        float v = 0.f;
        if(ih >= 0) v = x[((b*3 + ci)*256 + ih)*256 + tid];
        xs[r][tid + 1] = v;
        if(tid == 0) xs[r][0] = 0.f;
    }
    __syncthreads();
    int co = tid >> 1, h = tid & 1;
    float wr[27];
    #pragma unroll
    for(int j = 0; j < 27; ++j) wr[j] = w[co*27 + j];
    float bz = bias[co];
    long obase = ((long)((b*128 + co)*128 + oh))*128 + h*64;
    #pragma unroll 4
    for(int i = 0; i < 64; ++i){
        int iw0 = 2*(h*64 + i);
        float acc = bz;
        #pragma unroll
        for(int r = 0; r < 9; ++r){
            acc = fmaf(xs[r][iw0+0], wr[r*3+0], acc);
            acc = fmaf(xs[r][iw0+1], wr[r*3+1], acc);
            acc = fmaf(xs[r][iw0+2], wr[r*3+2], acc);
        }
        y[obase + i] = acc;
    }
}

// ---------------- GN stats ----------------
__global__ void zero_stats_kernel(float* __restrict__ stats){
    stats[threadIdx.x] = 0.0f;   // 64 threads
}

__global__ void gn_stats_kernel(const float* __restrict__ x, float* __restrict__ stats,
                                int elems_per_group){
    const int EPB = 16384;
    long base = (long)blockIdx.x * EPB;
    int g = (int)(base / elems_per_group);
    float s = 0.f, ss = 0.f;
    for(int j = threadIdx.x; j < EPB; j += 256){
        float v = x[base + j];
        s += v; ss += v*v;
    }
    #pragma unroll
    for(int off = 32; off; off >>= 1){
        s  += __shfl_down(s,  off);
        ss += __shfl_down(ss, off);
    }
    __shared__ float ls[4], lss[4];
    int wid = threadIdx.x >> 6, lane = threadIdx.x & 63;
    if(lane == 0){ ls[wid] = s; lss[wid] = ss; }
    __syncthreads();
    if(threadIdx.x == 0){
        atomicAdd(&stats[g],      ls[0]+ls[1]+ls[2]+ls[3]);
        atomicAdd(&stats[32+g], lss[0]+lss[1]+lss[2]+lss[3]);
    }
}

// ---------------- GN1 apply + SiLU + NCHW -> padded channels-last bf16 ----------------
__global__ void gn1_transform_kernel(const float* __restrict__ y1, const float* __restrict__ stats,
                                     const float* __restrict__ w, const float* __restrict__ bias,
                                     u16* __restrict__ xt){
    __shared__ float tile[32][33];
    int b = blockIdx.z >> 7, ih = blockIdx.z & 127;
    int c0 = blockIdx.y * 32, w0 = blockIdx.x * 32;
    int tx = threadIdx.x, ty = threadIdx.y;   // 32 x 8
    const float cnt = 16.f * 128.f * 128.f;
    #pragma unroll
    for(int i = 0; i < 4; ++i){
        int ci = c0 + ty + i*8;
        int g = b*8 + (ci >> 4);
        float mean = stats[g] / cnt;
        float var  = stats[32+g] / cnt - mean*mean;
        float rstd = rsqrtf(var + 1e-5f);
        float v = y1[(((long)(b*C1 + ci))*H1 + ih)*W1 + w0 + tx];
        tile[ty + i*8][tx] = dsilu((v - mean) * rstd * w[ci] + bias[ci]);
    }
    __syncthreads();
    #pragma unroll
    for(int i = 0; i < 4; ++i){
        int iwl = ty + i*8;
        xt[((long)(b*130 + ih + 1)*130 + (w0 + iwl + 1))*128 + c0 + tx] = f2bf(tile[tx][iwl]);
    }
}

// ---------------- conv2 as bf16 MFMA implicit GEMM ----------------
__global__ __launch_bounds__(256) void conv2gemm_bf16_kernel(
        const u16* __restrict__ xt, const u16* __restrict__ w2,
        const float* __restrict__ bias, float* __restrict__ y2t){
    __shared__ u16 Asm[128*32];
    __shared__ u16 Bsm[128*32];
    int m0 = blockIdx.x * 128, n0 = blockIdx.y * 128;
    int tid = threadIdx.x;
    long abase[2]; const u16* bbase[2];
    #pragma unroll
    for(int it = 0; it < 2; ++it){
        int c = it*256 + tid;
        int r = c >> 2, q = (c & 3) * 8;
        int m = m0 + r;
        int b = m >> 12, oh = (m >> 6) & 63, ow = m & 63;
        abase[it] = ((long)(b*130 + 2*oh)*130 + 2*ow)*128 + q;
        bbase[it] = w2 + (long)(n0 + r)*1152 + q;
    }
    int wave = tid >> 6, lane = tid & 63;
    int wr = wave >> 1, wc = wave & 1;
    int lm = lane & 15, lq = lane >> 4;
    f32x4 acc[4][4] = {};
    #pragma unroll 1
    for(int p = 0; p < 9; ++p){
        int kh = p / 3, kw = p - 3*kh;
        int aoff = (kh*130 + kw)*128;
        #pragma unroll 1
        for(int ci0 = 0; ci0 < 128; ci0 += 32){
            #pragma unroll
            for(int it = 0; it < 2; ++it){
                int c = it*256 + tid;
                GLL16(xt + abase[it] + aoff + ci0, &Asm[c*8]);
                GLL16(bbase[it] + p*128 + ci0, &Bsm[c*8]);
            }
            __syncthreads();
            short8 af[4], bf[4];
            #pragma unroll
            for(int i = 0; i < 4; ++i){
                af[i] = *(const short8*)&Asm[(wr*64 + i*16 + lm)*32 + lq*8];
                bf[i] = *(const short8*)&Bsm[(wc*64 + i*16 + lm)*32 + lq*8];
            }
            #pragma unroll
            for(int i = 0; i < 4; ++i)
                #pragma unroll
                for(int j = 0; j < 4; ++j)
                    acc[i][j] = __builtin_amdgcn_mfma_f32_16x16x32_bf16(af[i], bf[j], acc[i][j], 0, 0, 0);
            __syncthreads();
        }
    }
    #pragma unroll
    for(int i = 0; i < 4; ++i){
        long row = m0 + wr*64 + i*16 + lq*4;
        #pragma unroll
        for(int j = 0; j < 4; ++j){
            int col = n0 + wc*64 + j*16 + lm;
            float bz = bias[col];
            #pragma unroll
            for(int r = 0; r < 4; ++r)
                y2t[(row + r)*256L + col] = acc[i][j][r] + bz;
        }
    }
}

// ---------------- GN2 stats over [m][c] ----------------
__global__ void gn2t_stats_kernel(const float* __restrict__ y2t, float* __restrict__ stats){
    int b = blockIdx.y;
    long row0 = (long)b*LSEQ + blockIdx.x*64;
    int c = threadIdx.x;
    float s = 0.f, ss = 0.f;
    for(int r = 0; r < 64; ++r){
        float v = y2t[(row0 + r)*C2 + c];
        s += v; ss += v*v;
    }
    #pragma unroll
    for(int off = 16; off; off >>= 1){
        s  += __shfl_down(s,  off);
        ss += __shfl_down(ss, off);
    }
    if((c & 31) == 0){
        int g = b*8 + (c >> 5);
        atomicAdd(&stats[g], s);
        atomicAdd(&stats[32+g], ss);
    }
}

// ---------------- GN2 apply + SiLU -> s, fused LayerNorm(layer 0) -> xln_bf ----------------
__global__ void gn2t_apply_ln_kernel(const float* __restrict__ y2t, const float* __restrict__ stats,
                                     const float* __restrict__ gw, const float* __restrict__ gb,
                                     const float* __restrict__ lw, const float* __restrict__ lb,
                                     float* __restrict__ s, u16* __restrict__ xln){
    long row = blockIdx.x;                        // 16384 rows
    int c = threadIdx.x;                          // 256
    int b = (int)(row >> 12);
    int g = b*8 + (c >> 5);
    const float cnt = 32.f * (float)LSEQ;
    float mean = stats[g] / cnt;
    float var  = stats[32+g] / cnt - mean*mean;
    float rstd = rsqrtf(var + 1e-5f);
    float v = dsilu((y2t[row*HID + c] - mean) * rstd * gw[c] + gb[c]);
    s[row*HID + c] = v;
    // row LayerNorm
    float sm = v, sq = v*v;
    #pragma unroll
    for(int off = 32; off; off >>= 1){
        sm += __shfl_down(sm, off);
        sq += __shfl_down(sq, off);
    }
    __shared__ float pa[4], pb[4], res[2];
    int wid = c >> 6, lane = c & 63;
    if(lane == 0){ pa[wid] = sm; pb[wid] = sq; }
    __syncthreads();
    if(c == 0){
        float t  = pa[0]+pa[1]+pa[2]+pa[3];
        float tt = pb[0]+pb[1]+pb[2]+pb[3];
        float m2 = t / 256.f;
        float v2 = tt / 256.f - m2*m2;
        res[0] = m2; res[1] = rsqrtf(v2 + 1e-5f);
    }
    __syncthreads();
    xln[row*HID + c] = f2bf((v - res[0]) * res[1] * lw[c] + lb[c]);
}

// ---------------- bf16 MFMA GEMM: C[M,N] = A[M,K] * B[N,K]^T ----------------
// mode 0: fp32 store, 2: bf16 store
__global__ __launch_bounds__(256) void gemm_bf16_kernel(
        const u16* __restrict__ A, const u16* __restrict__ B, void* __restrict__ Cv,
        int K, int Nact, int ldc, int mode){
    __shared__ u16 Asm[128*32];
    __shared__ u16 Bsm[128*32];
    int m0 = blockIdx.x * 128, n0 = blockIdx.y * 128;
    int tid = threadIdx.x;
    int wave = tid >> 6, lane = tid & 63;
    int wr = wave >> 1, wc = wave & 1;
    int lm = lane & 15, lq = lane >> 4;
    f32x4 acc[4][4] = {};
    for(int k0 = 0; k0 < K; k0 += 32){
        #pragma unroll
        for(int it = 0; it < 2; ++it){
            int c = it*256 + tid;
            int row = c >> 2, kq = (c & 3) * 8;
            GLL16(A + (long)(m0 + row)*K + k0 + kq, &Asm[c*8]);
            GLL16(B + (long)(n0 + row)*K + k0 + kq, &Bsm[c*8]);
        }
        __syncthreads();
        short8 af[4], bf[4];
        #pragma unroll
        for(int i = 0; i < 4; ++i){
            af[i] = *(const short8*)&Asm[(wr*64 + i*16 + lm)*32 + lq*8];
            bf[i] = *(const short8*)&Bsm[(wc*64 + i*16 + lm)*32 + lq*8];
        }
        #pragma unroll
        for(int i = 0; i < 4; ++i)
            #pragma unroll
            for(int j = 0; j < 4; ++j)
                acc[i][j] = __builtin_amdgcn_mfma_f32_16x16x32_bf16(af[i], bf[j], acc[i][j], 0, 0, 0);
        __syncthreads();
    }
    #pragma unroll
    for(int i = 0; i < 4; ++i){
        long row = m0 + wr*64 + i*16 + lq*4;
        #pragma unroll
        for(int j = 0; j < 4; ++j){
            int col = n0 + wc*64 + j*16 + lm;
            if(col < Nact){
                #pragma unroll
                for(int r = 0; r < 4; ++r){
                    long idx = (row + r)*(long)ldc + col;
                    if(mode == 2) ((u16*)Cv)[idx] = f2bf(acc[i][j][r]);
                    else          ((float*)Cv)[idx] = acc[i][j][r];
                }
            }
        }
    }
}

// ---------------- out_proj + residual + LayerNorm fused ----------------
__global__ __launch_bounds__(256) void gemm_out_ln_kernel(
        const u16* __restrict__ A, const u16* __restrict__ B,
        float* __restrict__ s, u16* __restrict__ xln,
        const float* __restrict__ lw, const float* __restrict__ lb){
    __shared__ u16 Asm[64*32];    // 4 KB
    __shared__ u16 Bsm[256*32];   // 16 KB
    int m0 = blockIdx.x * 64;
    int tid = threadIdx.x;
    int w = tid >> 6, lane = tid & 63;
    int lm = lane & 15, lq = lane >> 4;
    f32x4 acc[16] = {};
    for(int k0 = 0; k0 < 512; k0 += 32){
        {
            int row = tid >> 2, kq = (tid & 3) * 8;
            GLL16(A + (long)(m0 + row)*512 + k0 + kq, &Asm[tid*8]);
        }
        #pragma unroll
        for(int it = 0; it < 4; ++it){
            int c = it*256 + tid;
            int row = c >> 2, kq = (c & 3) * 8;
            GLL16(B + (long)row*512 + k0 + kq, &Bsm[c*8]);
        }
        __syncthreads();
        short8 af = *(const short8*)&Asm[(w*16 + lm)*32 + lq*8];
        #pragma unroll
        for(int j = 0; j < 16; ++j){
            short8 bf = *(const short8*)&Bsm[(j*16 + lm)*32 + lq*8];
            acc[j] = __builtin_amdgcn_mfma_f32_16x16x32_bf16(af, bf, acc[j], 0, 0, 0);
        }
        __syncthreads();
    }
    int row0 = m0 + w*16 + lq*4;
    float psum[4] = {0.f,0.f,0.f,0.f}, psq[4] = {0.f,0.f,0.f,0.f};
    #pragma unroll
    for(int j = 0; j < 16; ++j){
        int col = j*16 + lm;
        #pragma unroll
        for(int r = 0; r < 4; ++r){
            long idx = (long)(row0 + r)*HID + col;
            float v = s[idx] + acc[j][r];
            acc[j][r] = v;
            s[idx] = v;
            psum[r] += v; psq[r] += v*v;
        }
    }
    #pragma unroll
    for(int mask = 1; mask <= 8; mask <<= 1){
        #pragma unroll
        for(int r = 0; r < 4; ++r){
            psum[r] += __shfl_xor(psum[r], mask);
            psq[r]  += __shfl_xor(psq[r],  mask);
        }
    }
    float mean[4], rstd[4];
    #pragma unroll
    for(int r = 0; r < 4; ++r){
        mean[r] = psum[r] * (1.f/256.f);
        float var = psq[r] * (1.f/256.f) - mean[r]*mean[r];
        rstd[r] = rsqrtf(var + 1e-5f);
    }
    #pragma unroll
    for(int j = 0; j < 16; ++j){
        int col = j*16 + lm;
        float wv = lw[col], bv = lb[col];
        #pragma unroll
        for(int r = 0; r < 4; ++r){
            long idx = (long)(row0 + r)*HID + col;
            xln[idx] = f2bf((acc[j][r] - mean[r]) * rstd[r] * wv + bv);
        }
    }
}

// ---------------- depthwise causal conv1d (k=4) + SiLU; bf16 in, bf16 out ----------------
__global__ void conv1d_silu_kernel(const u16* __restrict__ xz, const float* __restrict__ w,
                                   const float* __restrict__ bias, u16* __restrict__ xcv){
    int idx = blockIdx.x * 256 + threadIdx.x;    // 8388608
    int d = idx & 511, l = (idx >> 9) & 4095;
    const float* wp = w + d*4;
    float acc = bias[d];
    const u16* xp = xz + ((long)(idx >> 9))*(2*DIN) + d;
    #pragma unroll
    for(int j = 0; j < 4; ++j){
        int t = l - 3 + j;
        if(t >= 0) acc = fmaf(bf2f(xp[(long)(j-3)*(2*DIN)]), wp[j], acc);
    }
    xcv[idx] = f2bf(dsilu(acc));
}

// ---------------- dt_proj + softplus -> bf16 dv ----------------
__global__ void dtproj_kernel(const float* __restrict__ xdbl, const float* __restrict__ w,
                              const float* __restrict__ bias, u16* __restrict__ dv){
    int idx = blockIdx.x * 256 + threadIdx.x;    // 8388608
    int d = idx & 511;
    long m = idx >> 9;
    const float* dtv = xdbl + m*48;
    const float* wp  = w + d*16;
    float acc = bias[d];
    #pragma unroll
    for(int r = 0; r < 16; ++r) acc = fmaf(dtv[r], wp[r], acc);
    float v = (acc > 20.f) ? acc : log1pf(__expf(acc));
    dv[idx] = f2bf(v);
}

// ---------------- scan phase 1: reads dv; per-chunk (prod a, h_end) ----------------
__global__ __launch_bounds__(256) void scan1_kernel(
        const u16* __restrict__ xcvb, const u16* __restrict__ dvin,
        const float* __restrict__ xdbl, const float* __restrict__ Alog,
        float* __restrict__ aprod, float* __restrict__ hend){
    int d = blockIdx.y * 256 + threadIdx.x;
    int c = blockIdx.x;
    int b = blockIdx.z;
    __shared__ float bm[LCH][16];
    {
        int t = threadIdx.x >> 4, n = threadIdx.x & 15;
        #pragma unroll
        for(int it = 0; it < 2; ++it){
            long p = ((long)(b*LSEQ + c*LCH + t + it*16))*48;
            bm[t + it*16][n] = xdbl[p + 16 + n];
        }
    }
    __syncthreads();
    float An[16];
    #pragma unroll
    for(int n = 0; n < 16; ++n)
        An[n] = -__expf(Alog[d*16 + n]);
    float An0 = An[0];
    bool structural = true;
    #pragma unroll
    for(int n = 0; n < 16; ++n)
        structural = structural && (fabsf(An[n] - (float)(n+1)*An0) <= 1e-3f*(float)(n+1));
    long base = ((long)(b*LSEQ + c*LCH))*DIN + d;
    long ob = (((long)(b*NCHUNK + c))*DIN + d)*16;
    if(structural){
        f32x2 h2[8];
        #pragma unroll
        for(int i = 0; i < 8; ++i) h2[i] = (f32x2){0.f, 0.f};
        float sumdv = 0.f;
        float xv_n = bf2f(xcvb[base]);
        float dv_n = bf2f(dvin[base]);
        for(int t = 0; t < LCH; ++t){
            float xv = xv_n, dv = dv_n;
            if(t + 1 < LCH){
                xv_n = bf2f(xcvb[base + (long)(t+1)*DIN]);
                dv_n = bf2f(dvin[base + (long)(t+1)*DIN]);
            }
            sumdv += dv;
            float db = dv * xv;
            float r1 = __expf(dv * An0);
            float r2 = r1 * r1;
            f32x2 rr = {r2, r2};
            f32x2 e2[8];
            e2[0] = (f32x2){r1, r2};
            #pragma unroll
            for(int i = 1; i < 8; ++i) e2[i] = e2[i-1] * rr;
            f32x2 db2 = {db, db};
            const f32x2* b2 = (const f32x2*)&bm[t][0];
            #pragma unroll
            for(int i = 0; i < 8; ++i) h2[i] = e2[i]*h2[i] + db2*b2[i];
        }
        float R = __expf(An0 * sumdv);
        float Rp = R;
        const float* hp = (const float*)h2;
        #pragma unroll
        for(int n = 0; n < 16; ++n){
            aprod[ob+n] = Rp; Rp *= R;
            hend[ob+n] = hp[n];
        }
    } else {
        float h[16], ap[16];
        #pragma unroll
        for(int n = 0; n < 16; ++n){ h[n] = 0.f; ap[n] = 1.f; }
        for(int t = 0; t < LCH; ++t){
            float dv = bf2f(dvin[base + (long)t*DIN]);
            float db = dv * bf2f(xcvb[base + (long)t*DIN]);
            #pragma unroll
            for(int n = 0; n < 16; ++n){
                float e = __expf(dv * An[n]);
                ap[n] *= e;
                h[n] = fmaf(e, h[n], db * bm[t][n]);
            }
        }
        #pragma unroll
        for(int n = 0; n < 16; ++n){ aprod[ob+n] = ap[n]; hend[ob+n] = h[n]; }
    }
}

// ---------------- scan phase 2: sequential combine, 8-deep load batching ----------------
__global__ void scan2_kernel(const float* __restrict__ aprod, const float* __restrict__ hend,
                             float* __restrict__ hinit){
    int idx = blockIdx.x * 256 + threadIdx.x;    // 32768
    int n = idx & 15, d = (idx >> 4) & 511, b = idx >> 13;
    const long stride = (long)DIN * 16;
    long p0 = (((long)(b*NCHUNK))*DIN + d)*16 + n;
    float h = 0.f;
    for(int c = 0; c < NCHUNK; c += 8){
        float a[8], e[8];
        #pragma unroll
        for(int j = 0; j < 8; ++j){
            long p = p0 + (long)(c + j)*stride;
            a[j] = aprod[p]; e[j] = hend[p];
        }
        #pragma unroll
        for(int j = 0; j < 8; ++j){
            hinit[p0 + (long)(c + j)*stride] = h;
            h = fmaf(a[j], h, e[j]);
        }
    }
}

// ---------------- scan phase 3: reads dv; replay + epilogue -> bf16 y ----------------
__global__ __launch_bounds__(256) void scan3_kernel(
        const u16* __restrict__ xcvb, const u16* __restrict__ dvin,
        const float* __restrict__ xdbl, const float* __restrict__ Alog,
        const float* __restrict__ hinit, const float* __restrict__ Dp,
        const u16* __restrict__ xz, u16* __restrict__ yout){
    int d = blockIdx.y * 256 + threadIdx.x;
    int c = blockIdx.x;
    int b = blockIdx.z;
    __shared__ float bm[LCH][16], cm[LCH][16];
    {
        int t = threadIdx.x >> 4, n = threadIdx.x & 15;
        #pragma unroll
        for(int it = 0; it < 2; ++it){
            long p = ((long)(b*LSEQ + c*LCH + t + it*16))*48;
            bm[t + it*16][n] = xdbl[p + 16 + n];
            cm[t + it*16][n] = xdbl[p + 32 + n];
        }
    }
    __syncthreads();
    float An[16];
    long hb = (((long)(b*NCHUNK + c))*DIN + d)*16;
    #pragma unroll
    for(int n = 0; n < 16; ++n)
        An[n] = -__expf(Alog[d*16 + n]);
    float An0 = An[0];
    bool structural = true;
    #pragma unroll
    for(int n = 0; n < 16; ++n)
        structural = structural && (fabsf(An[n] - (float)(n+1)*An0) <= 1e-3f*(float)(n+1));
    float Dv = Dp[d];
    long base  = ((long)(b*LSEQ + c*LCH))*DIN + d;
    long zbase = ((long)(b*LSEQ + c*LCH))*(2*DIN) + DIN + d;
    if(structural){
        f32x2 h2[8];
        {
            const f32x2* hi = (const f32x2*)&hinit[hb];
            #pragma unroll
            for(int i = 0; i < 8; ++i) h2[i] = hi[i];
        }
        float xv_n = bf2f(xcvb[base]);
        float z_n  = bf2f(xz[zbase]);
        float dv_n = bf2f(dvin[base]);
        for(int t = 0; t < LCH; ++t){
            float xv = xv_n, z = z_n, dv = dv_n;
            if(t + 1 < LCH){
                xv_n = bf2f(xcvb[base + (long)(t+1)*DIN]);
                z_n  = bf2f(xz[zbase + (long)(t+1)*(2*DIN)]);
                dv_n = bf2f(dvin[base + (long)(t+1)*DIN]);
            }
            float db = dv * xv;
            float r1 = __expf(dv * An0);
            float r2 = r1 * r1;
            f32x2 rr = {r2, r2};
            f32x2 e2[8];
            e2[0] = (f32x2){r1, r2};
            #pragma unroll
            for(int i = 1; i < 8; ++i) e2[i] = e2[i-1] * rr;
            f32x2 db2 = {db, db};
            const f32x2* b2 = (const f32x2*)&bm[t][0];
            const f32x2* c2 = (const f32x2*)&cm[t][0];
            f32x2 y2 = {0.f, 0.f};
            #pragma unroll
            for(int i = 0; i < 8; ++i){
                h2[i] = e2[i]*h2[i] + db2*b2[i];
                y2 = y2 + h2[i]*c2[i];
            }
            float y = y2[0] + y2[1];
            y = fmaf(xv, Dv, y);
            yout[base + (long)t*DIN] = f2bf(y * dsilu(z));
        }
    } else {
        float h[16];
        #pragma unroll
        for(int n = 0; n < 16; ++n) h[n] = hinit[hb + n];
        for(int t = 0; t < LCH; ++t){
            float dv = bf2f(dvin[base + (long)t*DIN]);
            float xv = bf2f(xcvb[base + (long)t*DIN]);
            float db = dv * xv;
            float y = 0.f;
            #pragma unroll
            for(int n = 0; n < 16; ++n){
                float e = __expf(dv * An[n]);
                h[n] = fmaf(e, h[n], db * bm[t][n]);
                y = fmaf(h[n], cm[t][n], y);
            }
            y = fmaf(xv, Dv, y);
            float z = bf2f(xz[zbase + (long)t*(2*DIN)]);
            yout[base + (long)t*DIN] = f2bf(y * dsilu(z));
        }
    }
}

// ---------------- final copy ----------------
__global__ void copyout_kernel(const float* __restrict__ s, float* __restrict__ out, int out_size){
    int idx = blockIdx.x * 256 + threadIdx.x;
    if(idx >= out_size) return;
    out[idx] = (idx < BB*LSEQ*HID) ? s[idx] : 64.0f;
}

extern "C" void kernel_launch(void* const* d_in, const int* in_sizes, int n_in,
                              void* d_out, int out_size, void* d_ws, size_t ws_size,
                              hipStream_t stream){
    const float* x        = (const float*)d_in[0];
    const float* conv1_w  = (const float*)d_in[1];
    const float* conv1_b  = (const float*)d_in[2];
    const float* gn1_w    = (const float*)d_in[3];
    const float* gn1_b    = (const float*)d_in[4];
    const float* conv2_w  = (const float*)d_in[5];
    const float* conv2_b  = (const float*)d_in[6];
    const float* gn2_w    = (const float*)d_in[7];
    const float* gn2_b    = (const float*)d_in[8];
    const float* ln_w     = (const float*)d_in[9];
    const float* ln_b     = (const float*)d_in[10];
    const float* in_proj  = (const float*)d_in[11];
    const float* c1d_w    = (const float*)d_in[12];
    const float* c1d_b    = (const float*)d_in[13];
    const float* x_proj   = (const float*)d_in[14];
    const float* dt_w     = (const float*)d_in[15];
    const float* dt_b     = (const float*)d_in[16];
    const float* A_log    = (const float*)d_in[17];
    const float* Dvec     = (const float*)d_in[18];
    const float* out_proj = (const float*)d_in[19];

    float* ws = (float*)d_ws;
    float* s      = ws;                       // 4,194,304 f
    u16*   xz_bf  = (u16*)(ws + 4194304);     // 16,777,216 u16 (8,388,608 f)
    float* y1     = ws + 4194304;             // alias: y1 fp32 (stem only)
    u16*   xt     = (u16*)(ws + 12582912);    // 8,652,800 u16 (4,326,400 f)
    u16*   xcv_bf = (u16*)(ws + 16909312);    // 8,388,608 u16 (4,194,304 f)
    float* y2t    = ws + 16909312;            // alias: y2t fp32 (stem only)
    u16*   xln_bf = (u16*)(ws + 21103616);    // 4,194,304 u16 (2,097,152 f)
    float* xdbl   = ws + 23200768;            // 786,432 f
    float* aprod  = ws + 23987200;            // 4,194,304 f
    float* hendb  = ws + 28181504;            // 4,194,304 f
    u16*   y_bf   = (u16*)aprod;              // alias: 8,388,608 u16 fits in aprod
    float* hinit  = ws + 32375808;            // 4,194,304 f
    float* stats  = ws + 36570112;            // 64 f
    u16*   ipw_bf = (u16*)(ws + 36570176);    // 1,048,576 u16 (524,288 f)
    u16*   xpw_bf = ipw_bf + 1048576;         //   262,144 u16 (131,072 f)
    u16*   opw_bf = xpw_bf + 262144;          //   524,288 u16 (262,144 f)
    u16*   c2w_bf = opw_bf + 524288;          //   294,912 u16 (147,456 f)
    u16*   dv_bf  = (u16*)(ws + 37635200);    // 8,388,608 u16 (4,194,304 f) -> end 41,829,504 f

    // ---- weight prep ----
    f2bf_kernel<<<4096, 256, 0, stream>>>(in_proj, ipw_bf);
    f2bf_kernel<<<2048, 256, 0, stream>>>(out_proj, opw_bf);
    xpw_pad_kernel<<<1024, 256, 0, stream>>>(x_proj, xpw_bf);
    c2w_prep_kernel<<<1152, 256, 0, stream>>>(conv2_w, c2w_bf);

    // ---- stem ----
    conv1_kernel<<<dim3(128,4), 256, 0, stream>>>(x, conv1_w, conv1_b, y1);
    zero_stats_kernel<<<1, 64, 0, stream>>>(stats);
    gn_stats_kernel<<<512, 256, 0, stream>>>(y1, stats, 16*H1*W1);
    xt_zero_kernel<<<16900, 256, 0, stream>>>((unsigned*)xt);
    gn1_transform_kernel<<<dim3(4,4,512), dim3(32,8), 0, stream>>>(y1, stats, gn1_w, gn1_b, xt);
    conv2gemm_bf16_kernel<<<dim3(128,2), 256, 0, stream>>>(xt, c2w_bf, conv2_b, y2t);
    zero_stats_kernel<<<1, 64, 0, stream>>>(stats);
    gn2t_stats_kernel<<<dim3(64,4), 256, 0, stream>>>(y2t, stats);
    gn2t_apply_ln_kernel<<<16384, 256, 0, stream>>>(y2t, stats, gn2_w, gn2_b,
                                                    ln_w, ln_b, s, xln_bf);

    // ---- 4 mamba layers ----
    for(int layer = 0; layer < NL; ++layer){
        const float* cw  = c1d_w + (long)layer*DIN*4;
        const float* cb  = c1d_b + (long)layer*DIN;
        const float* dpw = dt_w  + (long)layer*DIN*DTR;
        const float* dpb = dt_b  + (long)layer*DIN;
        const float* Al  = A_log + (long)layer*DIN*DST;
        const float* Dl  = Dvec  + (long)layer*DIN;
        int lnext = (layer + 1) & 3;   // ln params for the NEXT layer's input

        gemm_bf16_kernel<<<dim3(128,8), 256, 0, stream>>>(
            xln_bf, ipw_bf + (long)layer*1024*256, xz_bf, HID, 2*DIN, 2*DIN, 2);
        conv1d_silu_kernel<<<32768, 256, 0, stream>>>(xz_bf, cw, cb, xcv_bf);
        gemm_bf16_kernel<<<dim3(128,1), 256, 0, stream>>>(
            xcv_bf, xpw_bf + (long)layer*128*512, xdbl, DIN, 48, 48, 0);
        dtproj_kernel<<<32768, 256, 0, stream>>>(xdbl, dpw, dpb, dv_bf);
        scan1_kernel<<<dim3(NCHUNK,2,BB), 256, 0, stream>>>(
            xcv_bf, dv_bf, xdbl, Al, aprod, hendb);
        scan2_kernel<<<128, 256, 0, stream>>>(aprod, hendb, hinit);
        scan3_kernel<<<dim3(NCHUNK,2,BB), 256, 0, stream>>>(
            xcv_bf, dv_bf, xdbl, Al, hinit, Dl, xz_bf, y_bf);
        gemm_out_ln_kernel<<<256, 256, 0, stream>>>(
            y_bf, opw_bf + (long)layer*256*512, s, xln_bf,
            ln_w + lnext*HID, ln_b + lnext*HID);
    }

    copyout_kernel<<<(out_size + 255)/256, 256, 0, stream>>>(s, (float*)d_out, out_size);
}

// Round 10
// 865.629 us; speedup vs baseline: 1.3823x; 1.2319x over previous
//
#include <hip/hip_runtime.h>
#include <math.h>

#define BB 4
#define C1 128
#define H1 128
#define W1 128
#define C2 256
#define H2 64
#define W2 64
#define LSEQ 4096
#define HID 256
#define DIN 512
#define DST 16
#define DTR 16
#define NL 4
#define NCHUNK 128
#define LCH 32

typedef unsigned short u16;
using short8 = __attribute__((ext_vector_type(8))) short;
using f32x4  = __attribute__((ext_vector_type(4))) float;
using f32x2  = __attribute__((ext_vector_type(2))) float;

static __device__ __forceinline__ float dsilu(float x){
    return x / (1.0f + __expf(-x));
}
static __device__ __forceinline__ u16 f2bf(float f){
    unsigned u = __float_as_uint(f);
    u += 0x7FFF + ((u >> 16) & 1);
    return (u16)(u >> 16);
}
static __device__ __forceinline__ float bf2f(u16 v){
    return __uint_as_float(((unsigned)v) << 16);
}

#define GLL16(g, l) __builtin_amdgcn_global_load_lds( \
    (const __attribute__((address_space(1))) void*)(g), \
    (__attribute__((address_space(3))) void*)(l), 16, 0, 0)

// ---------------- weight prep ----------------
__global__ void f2bf_kernel(const float* __restrict__ src, u16* __restrict__ dst){
    int idx = blockIdx.x * 256 + threadIdx.x;
    dst[idx] = f2bf(src[idx]);
}
// combined dt/BC weight: wcomb[layer][n][k], n<512: (dpw @ xpw[0:16])[n][k];
// n in 512..543: xpw rows 16..47; rest zero.
__global__ void wdt_prep_kernel(const float* __restrict__ xpw, const float* __restrict__ dpw,
                                u16* __restrict__ wcomb){
    int idx = blockIdx.x * 256 + threadIdx.x;   // 4*640*512 = 1,310,720
    int k = idx & 511;
    int n = (idx >> 9) % 640;
    int layer = idx / (640*512);
    u16 val = 0;
    if(n < 512){
        const float* dp = dpw + ((long)layer*512 + n)*16;
        const float* xp = xpw + (long)layer*48*512 + k;
        float acc = 0.f;
        #pragma unroll
        for(int r = 0; r < 16; ++r) acc = fmaf(dp[r], xp[(long)r*512], acc);
        val = f2bf(acc);
    } else if(n < 544){
        int row = n - 512 + 16;
        val = f2bf(xpw[((long)layer*48 + row)*512 + k]);
    }
    wcomb[((long)layer*640 + n)*512 + k] = val;
}
// conv2_w [co][ci][kh][kw] -> w2 [co][p=kh*3+kw][ci] bf16
__global__ void c2w_prep_kernel(const float* __restrict__ src, u16* __restrict__ dst){
    int idx = blockIdx.x * 256 + threadIdx.x;   // 294912
    int ci = idx & 127, p = (idx >> 7) % 9, co = idx / (9*128);
    int kh = p / 3, kw = p - 3*kh;
    dst[idx] = f2bf(src[((co*128 + ci)*3 + kh)*3 + kw]);
}
__global__ void xt_zero_kernel(unsigned* __restrict__ xt){
    xt[blockIdx.x * 256 + threadIdx.x] = 0;     // 4,326,400 uints
}

// ---------------- conv1 via LDS row staging ----------------
__global__ __launch_bounds__(256) void conv1_kernel(
        const float* __restrict__ x, const float* __restrict__ w,
        const float* __restrict__ bias, float* __restrict__ y){
    __shared__ float xs[9][260];
    int oh = blockIdx.x, b = blockIdx.y;
    int tid = threadIdx.x;
    #pragma unroll
    for(int r = 0; r < 9; ++r){
        int ci = r / 3, kh = r - 3*ci;
        int ih = 2*oh - 1 + kh;
        float v = 0.f;
        if(ih >= 0) v = x[((b*3 + ci)*256 + ih)*256 + tid];
        xs[r][tid + 1] = v;
        if(tid == 0) xs[r][0] = 0.f;
    }
    __syncthreads();
    int co = tid >> 1, h = tid & 1;
    float wr[27];
    #pragma unroll
    for(int j = 0; j < 27; ++j) wr[j] = w[co*27 + j];
    float bz = bias[co];
    long obase = ((long)((b*128 + co)*128 + oh))*128 + h*64;
    #pragma unroll 4
    for(int i = 0; i < 64; ++i){
        int iw0 = 2*(h*64 + i);
        float acc = bz;
        #pragma unroll
        for(int r = 0; r < 9; ++r){
            acc = fmaf(xs[r][iw0+0], wr[r*3+0], acc);
            acc = fmaf(xs[r][iw0+1], wr[r*3+1], acc);
            acc = fmaf(xs[r][iw0+2], wr[r*3+2], acc);
        }
        y[obase + i] = acc;
    }
}

// ---------------- GN stats ----------------
__global__ void zero_stats_kernel(float* __restrict__ stats){
    stats[threadIdx.x] = 0.0f;   // 64 threads
}

__global__ void gn_stats_kernel(const float* __restrict__ x, float* __restrict__ stats,
                                int elems_per_group){
    const int EPB = 16384;
    long base = (long)blockIdx.x * EPB;
    int g = (int)(base / elems_per_group);
    float s = 0.f, ss = 0.f;
    for(int j = threadIdx.x; j < EPB; j += 256){
        float v = x[base + j];
        s += v; ss += v*v;
    }
    #pragma unroll
    for(int off = 32; off; off >>= 1){
        s  += __shfl_down(s,  off);
        ss += __shfl_down(ss, off);
    }
    __shared__ float ls[4], lss[4];
    int wid = threadIdx.x >> 6, lane = threadIdx.x & 63;
    if(lane == 0){ ls[wid] = s; lss[wid] = ss; }
    __syncthreads();
    if(threadIdx.x == 0){
        atomicAdd(&stats[g],      ls[0]+ls[1]+ls[2]+ls[3]);
        atomicAdd(&stats[32+g], lss[0]+lss[1]+lss[2]+lss[3]);
    }
}

// ---------------- GN1 apply + SiLU + NCHW -> padded channels-last bf16 ----------------
__global__ void gn1_transform_kernel(const float* __restrict__ y1, const float* __restrict__ stats,
                                     const float* __restrict__ w, const float* __restrict__ bias,
                                     u16* __restrict__ xt){
    __shared__ float tile[32][33];
    int b = blockIdx.z >> 7, ih = blockIdx.z & 127;
    int c0 = blockIdx.y * 32, w0 = blockIdx.x * 32;
    int tx = threadIdx.x, ty = threadIdx.y;   // 32 x 8
    const float cnt = 16.f * 128.f * 128.f;
    #pragma unroll
    for(int i = 0; i < 4; ++i){
        int ci = c0 + ty + i*8;
        int g = b*8 + (ci >> 4);
        float mean = stats[g] / cnt;
        float var  = stats[32+g] / cnt - mean*mean;
        float rstd = rsqrtf(var + 1e-5f);
        float v = y1[(((long)(b*C1 + ci))*H1 + ih)*W1 + w0 + tx];
        tile[ty + i*8][tx] = dsilu((v - mean) * rstd * w[ci] + bias[ci]);
    }
    __syncthreads();
    #pragma unroll
    for(int i = 0; i < 4; ++i){
        int iwl = ty + i*8;
        xt[((long)(b*130 + ih + 1)*130 + (w0 + iwl + 1))*128 + c0 + tx] = f2bf(tile[tx][iwl]);
    }
}

// ---------------- conv2 as bf16 MFMA implicit GEMM ----------------
__global__ __launch_bounds__(256) void conv2gemm_bf16_kernel(
        const u16* __restrict__ xt, const u16* __restrict__ w2,
        const float* __restrict__ bias, float* __restrict__ y2t){
    __shared__ u16 Asm[128*32];
    __shared__ u16 Bsm[128*32];
    int m0 = blockIdx.x * 128, n0 = blockIdx.y * 128;
    int tid = threadIdx.x;
    long abase[2]; const u16* bbase[2];
    #pragma unroll
    for(int it = 0; it < 2; ++it){
        int c = it*256 + tid;
        int r = c >> 2, q = (c & 3) * 8;
        int m = m0 + r;
        int b = m >> 12, oh = (m >> 6) & 63, ow = m & 63;
        abase[it] = ((long)(b*130 + 2*oh)*130 + 2*ow)*128 + q;
        bbase[it] = w2 + (long)(n0 + r)*1152 + q;
    }
    int wave = tid >> 6, lane = tid & 63;
    int wr = wave >> 1, wc = wave & 1;
    int lm = lane & 15, lq = lane >> 4;
    f32x4 acc[4][4] = {};
    #pragma unroll 1
    for(int p = 0; p < 9; ++p){
        int kh = p / 3, kw = p - 3*kh;
        int aoff = (kh*130 + kw)*128;
        #pragma unroll 1
        for(int ci0 = 0; ci0 < 128; ci0 += 32){
            #pragma unroll
            for(int it = 0; it < 2; ++it){
                int c = it*256 + tid;
                GLL16(xt + abase[it] + aoff + ci0, &Asm[c*8]);
                GLL16(bbase[it] + p*128 + ci0, &Bsm[c*8]);
            }
            __syncthreads();
            short8 af[4], bf[4];
            #pragma unroll
            for(int i = 0; i < 4; ++i){
                af[i] = *(const short8*)&Asm[(wr*64 + i*16 + lm)*32 + lq*8];
                bf[i] = *(const short8*)&Bsm[(wc*64 + i*16 + lm)*32 + lq*8];
            }
            #pragma unroll
            for(int i = 0; i < 4; ++i)
                #pragma unroll
                for(int j = 0; j < 4; ++j)
                    acc[i][j] = __builtin_amdgcn_mfma_f32_16x16x32_bf16(af[i], bf[j], acc[i][j], 0, 0, 0);
            __syncthreads();
        }
    }
    #pragma unroll
    for(int i = 0; i < 4; ++i){
        long row = m0 + wr*64 + i*16 + lq*4;
        #pragma unroll
        for(int j = 0; j < 4; ++j){
            int col = n0 + wc*64 + j*16 + lm;
            float bz = bias[col];
            #pragma unroll
            for(int r = 0; r < 4; ++r)
                y2t[(row + r)*256L + col] = acc[i][j][r] + bz;
        }
    }
}

// ---------------- GN2 stats over [m][c] ----------------
__global__ void gn2t_stats_kernel(const float* __restrict__ y2t, float* __restrict__ stats){
    int b = blockIdx.y;
    long row0 = (long)b*LSEQ + blockIdx.x*64;
    int c = threadIdx.x;
    float s = 0.f, ss = 0.f;
    for(int r = 0; r < 64; ++r){
        float v = y2t[(row0 + r)*C2 + c];
        s += v; ss += v*v;
    }
    #pragma unroll
    for(int off = 16; off; off >>= 1){
        s  += __shfl_down(s,  off);
        ss += __shfl_down(ss, off);
    }
    if((c & 31) == 0){
        int g = b*8 + (c >> 5);
        atomicAdd(&stats[g], s);
        atomicAdd(&stats[32+g], ss);
    }
}

// ---------------- GN2 apply + SiLU -> s, fused LayerNorm(layer 0) -> xln_bf ----------------
__global__ void gn2t_apply_ln_kernel(const float* __restrict__ y2t, const float* __restrict__ stats,
                                     const float* __restrict__ gw, const float* __restrict__ gb,
                                     const float* __restrict__ lw, const float* __restrict__ lb,
                                     float* __restrict__ s, u16* __restrict__ xln){
    long row = blockIdx.x;                        // 16384 rows
    int c = threadIdx.x;                          // 256
    int b = (int)(row >> 12);
    int g = b*8 + (c >> 5);
    const float cnt = 32.f * (float)LSEQ;
    float mean = stats[g] / cnt;
    float var  = stats[32+g] / cnt - mean*mean;
    float rstd = rsqrtf(var + 1e-5f);
    float v = dsilu((y2t[row*HID + c] - mean) * rstd * gw[c] + gb[c]);
    s[row*HID + c] = v;
    float sm = v, sq = v*v;
    #pragma unroll
    for(int off = 32; off; off >>= 1){
        sm += __shfl_down(sm, off);
        sq += __shfl_down(sq, off);
    }
    __shared__ float pa[4], pb[4], res[2];
    int wid = c >> 6, lane = c & 63;
    if(lane == 0){ pa[wid] = sm; pb[wid] = sq; }
    __syncthreads();
    if(c == 0){
        float t  = pa[0]+pa[1]+pa[2]+pa[3];
        float tt = pb[0]+pb[1]+pb[2]+pb[3];
        float m2 = t / 256.f;
        float v2 = tt / 256.f - m2*m2;
        res[0] = m2; res[1] = rsqrtf(v2 + 1e-5f);
    }
    __syncthreads();
    xln[row*HID + c] = f2bf((v - res[0]) * res[1] * lw[c] + lb[c]);
}

// ---------------- bf16 MFMA GEMM: C[M,N] = A[M,K] * B[N,K]^T ----------------
// mode 2: bf16 store (used for in_proj)
__global__ __launch_bounds__(256) void gemm_bf16_kernel(
        const u16* __restrict__ A, const u16* __restrict__ B, void* __restrict__ Cv,
        int K, int Nact, int ldc, int mode){
    __shared__ u16 Asm[128*32];
    __shared__ u16 Bsm[128*32];
    int m0 = blockIdx.x * 128, n0 = blockIdx.y * 128;
    int tid = threadIdx.x;
    int wave = tid >> 6, lane = tid & 63;
    int wr = wave >> 1, wc = wave & 1;
    int lm = lane & 15, lq = lane >> 4;
    f32x4 acc[4][4] = {};
    for(int k0 = 0; k0 < K; k0 += 32){
        #pragma unroll
        for(int it = 0; it < 2; ++it){
            int c = it*256 + tid;
            int row = c >> 2, kq = (c & 3) * 8;
            GLL16(A + (long)(m0 + row)*K + k0 + kq, &Asm[c*8]);
            GLL16(B + (long)(n0 + row)*K + k0 + kq, &Bsm[c*8]);
        }
        __syncthreads();
        short8 af[4], bf[4];
        #pragma unroll
        for(int i = 0; i < 4; ++i){
            af[i] = *(const short8*)&Asm[(wr*64 + i*16 + lm)*32 + lq*8];
            bf[i] = *(const short8*)&Bsm[(wc*64 + i*16 + lm)*32 + lq*8];
        }
        #pragma unroll
        for(int i = 0; i < 4; ++i)
            #pragma unroll
            for(int j = 0; j < 4; ++j)
                acc[i][j] = __builtin_amdgcn_mfma_f32_16x16x32_bf16(af[i], bf[j], acc[i][j], 0, 0, 0);
        __syncthreads();
    }
    #pragma unroll
    for(int i = 0; i < 4; ++i){
        long row = m0 + wr*64 + i*16 + lq*4;
        #pragma unroll
        for(int j = 0; j < 4; ++j){
            int col = n0 + wc*64 + j*16 + lm;
            if(col < Nact){
                #pragma unroll
                for(int r = 0; r < 4; ++r){
                    long idx = (row + r)*(long)ldc + col;
                    if(mode == 2) ((u16*)Cv)[idx] = f2bf(acc[i][j][r]);
                    else          ((float*)Cv)[idx] = acc[i][j][r];
                }
            }
        }
    }
}

// ---------------- fused dt-proj (softplus) + x_proj B/C GEMM ----------------
// A[16384,512] bf16, B = wcomb[640,512] bf16. Tiles 0..3: dv = softplus(acc+dpb) bf16.
// Tile 4: xdbl32[m][0..31] = acc fp32 (B rows 0..15, C rows 16..31).
__global__ __launch_bounds__(256) void gemm_dtbc_kernel(
        const u16* __restrict__ A, const u16* __restrict__ B,
        const float* __restrict__ dpb, u16* __restrict__ dv,
        float* __restrict__ xdbl32){
    __shared__ u16 Asm[128*32];
    __shared__ u16 Bsm[128*32];
    int m0 = blockIdx.x * 128, n0 = blockIdx.y * 128;
    int tid = threadIdx.x;
    int wave = tid >> 6, lane = tid & 63;
    int wr = wave >> 1, wc = wave & 1;
    int lm = lane & 15, lq = lane >> 4;
    f32x4 acc[4][4] = {};
    for(int k0 = 0; k0 < 512; k0 += 32){
        #pragma unroll
        for(int it = 0; it < 2; ++it){
            int c = it*256 + tid;
            int row = c >> 2, kq = (c & 3) * 8;
            GLL16(A + (long)(m0 + row)*512 + k0 + kq, &Asm[c*8]);
            GLL16(B + (long)(n0 + row)*512 + k0 + kq, &Bsm[c*8]);
        }
        __syncthreads();
        short8 af[4], bf[4];
        #pragma unroll
        for(int i = 0; i < 4; ++i){
            af[i] = *(const short8*)&Asm[(wr*64 + i*16 + lm)*32 + lq*8];
            bf[i] = *(const short8*)&Bsm[(wc*64 + i*16 + lm)*32 + lq*8];
        }
        #pragma unroll
        for(int i = 0; i < 4; ++i)
            #pragma unroll
            for(int j = 0; j < 4; ++j)
                acc[i][j] = __builtin_amdgcn_mfma_f32_16x16x32_bf16(af[i], bf[j], acc[i][j], 0, 0, 0);
        __syncthreads();
    }
    if(n0 < 512){
        #pragma unroll
        for(int i = 0; i < 4; ++i){
            long row = m0 + wr*64 + i*16 + lq*4;
            #pragma unroll
            for(int j = 0; j < 4; ++j){
                int col = n0 + wc*64 + j*16 + lm;
                float bz = dpb[col];
                #pragma unroll
                for(int r = 0; r < 4; ++r){
                    float v = acc[i][j][r] + bz;
                    v = (v > 20.f) ? v : __logf(1.f + __expf(v));
                    dv[(row + r)*512L + col] = f2bf(v);
                }
            }
        }
    } else {
        #pragma unroll
        for(int i = 0; i < 4; ++i){
            long row = m0 + wr*64 + i*16 + lq*4;
            #pragma unroll
            for(int j = 0; j < 4; ++j){
                int lcol = wc*64 + j*16 + lm;     // 0..127, valid < 32
                if(lcol < 32){
                    #pragma unroll
                    for(int r = 0; r < 4; ++r)
                        xdbl32[(row + r)*32L + lcol] = acc[i][j][r];
                }
            }
        }
    }
}

// ---------------- out_proj + residual + LayerNorm fused ----------------
__global__ __launch_bounds__(256) void gemm_out_ln_kernel(
        const u16* __restrict__ A, const u16* __restrict__ B,
        float* __restrict__ s, u16* __restrict__ xln,
        const float* __restrict__ lw, const float* __restrict__ lb){
    __shared__ u16 Asm[64*32];    // 4 KB
    __shared__ u16 Bsm[256*32];   // 16 KB
    int m0 = blockIdx.x * 64;
    int tid = threadIdx.x;
    int w = tid >> 6, lane = tid & 63;
    int lm = lane & 15, lq = lane >> 4;
    f32x4 acc[16] = {};
    for(int k0 = 0; k0 < 512; k0 += 32){
        {
            int row = tid >> 2, kq = (tid & 3) * 8;
            GLL16(A + (long)(m0 + row)*512 + k0 + kq, &Asm[tid*8]);
        }
        #pragma unroll
        for(int it = 0; it < 4; ++it){
            int c = it*256 + tid;
            int row = c >> 2, kq = (c & 3) * 8;
            GLL16(B + (long)row*512 + k0 + kq, &Bsm[c*8]);
        }
        __syncthreads();
        short8 af = *(const short8*)&Asm[(w*16 + lm)*32 + lq*8];
        #pragma unroll
        for(int j = 0; j < 16; ++j){
            short8 bf = *(const short8*)&Bsm[(j*16 + lm)*32 + lq*8];
            acc[j] = __builtin_amdgcn_mfma_f32_16x16x32_bf16(af, bf, acc[j], 0, 0, 0);
        }
        __syncthreads();
    }
    int row0 = m0 + w*16 + lq*4;
    float psum[4] = {0.f,0.f,0.f,0.f}, psq[4] = {0.f,0.f,0.f,0.f};
    #pragma unroll
    for(int j = 0; j < 16; ++j){
        int col = j*16 + lm;
        #pragma unroll
        for(int r = 0; r < 4; ++r){
            long idx = (long)(row0 + r)*HID + col;
            float v = s[idx] + acc[j][r];
            acc[j][r] = v;
            s[idx] = v;
            psum[r] += v; psq[r] += v*v;
        }
    }
    #pragma unroll
    for(int mask = 1; mask <= 8; mask <<= 1){
        #pragma unroll
        for(int r = 0; r < 4; ++r){
            psum[r] += __shfl_xor(psum[r], mask);
            psq[r]  += __shfl_xor(psq[r],  mask);
        }
    }
    float mean[4], rstd[4];
    #pragma unroll
    for(int r = 0; r < 4; ++r){
        mean[r] = psum[r] * (1.f/256.f);
        float var = psq[r] * (1.f/256.f) - mean[r]*mean[r];
        rstd[r] = rsqrtf(var + 1e-5f);
    }
    #pragma unroll
    for(int j = 0; j < 16; ++j){
        int col = j*16 + lm;
        float wv = lw[col], bv = lb[col];
        #pragma unroll
        for(int r = 0; r < 4; ++r){
            long idx = (long)(row0 + r)*HID + col;
            xln[idx] = f2bf((acc[j][r] - mean[r]) * rstd[r] * wv + bv);
        }
    }
}

// ---------------- depthwise causal conv1d (k=4) + SiLU; vectorized x8 over d ----------------
__global__ void conv1d_silu_kernel(const u16* __restrict__ xz, const float* __restrict__ w,
                                   const float* __restrict__ bias, u16* __restrict__ xcv){
    int idx = blockIdx.x * 256 + threadIdx.x;    // 1,048,576 threads
    int e = idx * 8;
    int d0 = e & 511;
    long m = e >> 9;
    int l = (int)(m & 4095);
    short8 xrow[4];
    const u16* xp = xz + m*(2*DIN) + d0;
    #pragma unroll
    for(int j = 0; j < 4; ++j){
        int t = l - 3 + j;
        if(t >= 0) xrow[j] = *(const short8*)(xp + (long)(j-3)*(2*DIN));
        else       xrow[j] = (short8){0,0,0,0,0,0,0,0};
    }
    float wv[8][4];
    #pragma unroll
    for(int k = 0; k < 8; k += 2){
        float4 a = *(const float4*)(w + (d0+k)*4);
        float4 b = *(const float4*)(w + (d0+k+1)*4);
        wv[k][0]=a.x; wv[k][1]=a.y; wv[k][2]=a.z; wv[k][3]=a.w;
        wv[k+1][0]=b.x; wv[k+1][1]=b.y; wv[k+1][2]=b.z; wv[k+1][3]=b.w;
    }
    float bz[8];
    {
        float4 a = *(const float4*)(bias + d0);
        float4 b = *(const float4*)(bias + d0 + 4);
        bz[0]=a.x; bz[1]=a.y; bz[2]=a.z; bz[3]=a.w;
        bz[4]=b.x; bz[5]=b.y; bz[6]=b.z; bz[7]=b.w;
    }
    short8 out;
    #pragma unroll
    for(int k = 0; k < 8; ++k){
        float acc = bz[k];
        #pragma unroll
        for(int j = 0; j < 4; ++j)
            acc = fmaf(bf2f((u16)xrow[j][k]), wv[k][j], acc);
        out[k] = (short)f2bf(dsilu(acc));
    }
    *(short8*)(xcv + m*DIN + d0) = out;
}

// ---------------- scan phase 1: reads dv; per-chunk (prod a, h_end) ----------------
__global__ __launch_bounds__(256) void scan1_kernel(
        const u16* __restrict__ xcvb, const u16* __restrict__ dvin,
        const float* __restrict__ xdbl32, const float* __restrict__ Alog,
        float* __restrict__ aprod, float* __restrict__ hend){
    int d = blockIdx.y * 256 + threadIdx.x;
    int c = blockIdx.x;
    int b = blockIdx.z;
    __shared__ float bm[LCH][16];
    {
        int t = threadIdx.x >> 4, n = threadIdx.x & 15;
        #pragma unroll
        for(int it = 0; it < 2; ++it){
            long p = ((long)(b*LSEQ + c*LCH + t + it*16))*32;
            bm[t + it*16][n] = xdbl32[p + n];
        }
    }
    __syncthreads();
    float An[16];
    #pragma unroll
    for(int n = 0; n < 16; ++n)
        An[n] = -__expf(Alog[d*16 + n]);
    float An0 = An[0];
    bool structural = true;
    #pragma unroll
    for(int n = 0; n < 16; ++n)
        structural = structural && (fabsf(An[n] - (float)(n+1)*An0) <= 1e-3f*(float)(n+1));
    long base = ((long)(b*LSEQ + c*LCH))*DIN + d;
    long ob = (((long)(b*NCHUNK + c))*DIN + d)*16;
    if(structural){
        f32x2 h2[8];
        #pragma unroll
        for(int i = 0; i < 8; ++i) h2[i] = (f32x2){0.f, 0.f};
        float sumdv = 0.f;
        float xv_n = bf2f(xcvb[base]);
        float dv_n = bf2f(dvin[base]);
        for(int t = 0; t < LCH; ++t){
            float xv = xv_n, dv = dv_n;
            if(t + 1 < LCH){
                xv_n = bf2f(xcvb[base + (long)(t+1)*DIN]);
                dv_n = bf2f(dvin[base + (long)(t+1)*DIN]);
            }
            sumdv += dv;
            float db = dv * xv;
            float r1 = __expf(dv * An0);
            float r2 = r1 * r1;
            f32x2 rr = {r2, r2};
            f32x2 e2[8];
            e2[0] = (f32x2){r1, r2};
            #pragma unroll
            for(int i = 1; i < 8; ++i) e2[i] = e2[i-1] * rr;
            f32x2 db2 = {db, db};
            const f32x2* b2 = (const f32x2*)&bm[t][0];
            #pragma unroll
            for(int i = 0; i < 8; ++i) h2[i] = e2[i]*h2[i] + db2*b2[i];
        }
        float R = __expf(An0 * sumdv);
        float Rp = R;
        const float* hp = (const float*)h2;
        #pragma unroll
        for(int n = 0; n < 16; ++n){
            aprod[ob+n] = Rp; Rp *= R;
            hend[ob+n] = hp[n];
        }
    } else {
        float h[16], ap[16];
        #pragma unroll
        for(int n = 0; n < 16; ++n){ h[n] = 0.f; ap[n] = 1.f; }
        for(int t = 0; t < LCH; ++t){
            float dv = bf2f(dvin[base + (long)t*DIN]);
            float db = dv * bf2f(xcvb[base + (long)t*DIN]);
            #pragma unroll
            for(int n = 0; n < 16; ++n){
                float e = __expf(dv * An[n]);
                ap[n] *= e;
                h[n] = fmaf(e, h[n], db * bm[t][n]);
            }
        }
        #pragma unroll
        for(int n = 0; n < 16; ++n){ aprod[ob+n] = ap[n]; hend[ob+n] = h[n]; }
    }
}

// ---------------- scan phase 2: sequential combine, 8-deep load batching ----------------
__global__ void scan2_kernel(const float* __restrict__ aprod, const float* __restrict__ hend,
                             float* __restrict__ hinit){
    int idx = blockIdx.x * 256 + threadIdx.x;    // 32768
    int n = idx & 15, d = (idx >> 4) & 511, b = idx >> 13;
    const long stride = (long)DIN * 16;
    long p0 = (((long)(b*NCHUNK))*DIN + d)*16 + n;
    float h = 0.f;
    for(int c = 0; c < NCHUNK; c += 8){
        float a[8], e[8];
        #pragma unroll
        for(int j = 0; j < 8; ++j){
            long p = p0 + (long)(c + j)*stride;
            a[j] = aprod[p]; e[j] = hend[p];
        }
        #pragma unroll
        for(int j = 0; j < 8; ++j){
            hinit[p0 + (long)(c + j)*stride] = h;
            h = fmaf(a[j], h, e[j]);
        }
    }
}

// ---------------- scan phase 3: reads dv; replay + epilogue -> bf16 y ----------------
__global__ __launch_bounds__(256) void scan3_kernel(
        const u16* __restrict__ xcvb, const u16* __restrict__ dvin,
        const float* __restrict__ xdbl32, const float* __restrict__ Alog,
        const float* __restrict__ hinit, const float* __restrict__ Dp,
        const u16* __restrict__ xz, u16* __restrict__ yout){
    int d = blockIdx.y * 256 + threadIdx.x;
    int c = blockIdx.x;
    int b = blockIdx.z;
    __shared__ float bm[LCH][16], cm[LCH][16];
    {
        int t = threadIdx.x >> 4, n = threadIdx.x & 15;
        #pragma unroll
        for(int it = 0; it < 2; ++it){
            long p = ((long)(b*LSEQ + c*LCH + t + it*16))*32;
            bm[t + it*16][n] = xdbl32[p + n];
            cm[t + it*16][n] = xdbl32[p + 16 + n];
        }
    }
    __syncthreads();
    float An[16];
    long hb = (((long)(b*NCHUNK + c))*DIN + d)*16;
    #pragma unroll
    for(int n = 0; n < 16; ++n)
        An[n] = -__expf(Alog[d*16 + n]);
    float An0 = An[0];
    bool structural = true;
    #pragma unroll
    for(int n = 0; n < 16; ++n)
        structural = structural && (fabsf(An[n] - (float)(n+1)*An0) <= 1e-3f*(float)(n+1));
    float Dv = Dp[d];
    long base  = ((long)(b*LSEQ + c*LCH))*DIN + d;
    long zbase = ((long)(b*LSEQ + c*LCH))*(2*DIN) + DIN + d;
    if(structural){
        f32x2 h2[8];
        {
            const f32x2* hi = (const f32x2*)&hinit[hb];
            #pragma unroll
            for(int i = 0; i < 8; ++i) h2[i] = hi[i];
        }
        float xv_n = bf2f(xcvb[base]);
        float z_n  = bf2f(xz[zbase]);
        float dv_n = bf2f(dvin[base]);
        for(int t = 0; t < LCH; ++t){
            float xv = xv_n, z = z_n, dv = dv_n;
            if(t + 1 < LCH){
                xv_n = bf2f(xcvb[base + (long)(t+1)*DIN]);
                z_n  = bf2f(xz[zbase + (long)(t+1)*(2*DIN)]);
                dv_n = bf2f(dvin[base + (long)(t+1)*DIN]);
            }
            float db = dv * xv;
            float r1 = __expf(dv * An0);
            float r2 = r1 * r1;
            f32x2 rr = {r2, r2};
            f32x2 e2[8];
            e2[0] = (f32x2){r1, r2};
            #pragma unroll
            for(int i = 1; i < 8; ++i) e2[i] = e2[i-1] * rr;
            f32x2 db2 = {db, db};
            const f32x2* b2 = (const f32x2*)&bm[t][0];
            const f32x2* c2 = (const f32x2*)&cm[t][0];
            f32x2 y2 = {0.f, 0.f};
            #pragma unroll
            for(int i = 0; i < 8; ++i){
                h2[i] = e2[i]*h2[i] + db2*b2[i];
                y2 = y2 + h2[i]*c2[i];
            }
            float y = y2[0] + y2[1];
            y = fmaf(xv, Dv, y);
            yout[base + (long)t*DIN] = f2bf(y * dsilu(z));
        }
    } else {
        float h[16];
        #pragma unroll
        for(int n = 0; n < 16; ++n) h[n] = hinit[hb + n];
        for(int t = 0; t < LCH; ++t){
            float dv = bf2f(dvin[base + (long)t*DIN]);
            float xv = bf2f(xcvb[base + (long)t*DIN]);
            float db = dv * xv;
            float y = 0.f;
            #pragma unroll
            for(int n = 0; n < 16; ++n){
                float e = __expf(dv * An[n]);
                h[n] = fmaf(e, h[n], db * bm[t][n]);
                y = fmaf(h[n], cm[t][n], y);
            }
            y = fmaf(xv, Dv, y);
            float z = bf2f(xz[zbase + (long)t*(2*DIN)]);
            yout[base + (long)t*DIN] = f2bf(y * dsilu(z));
        }
    }
}

// ---------------- final copy ----------------
__global__ void copyout_kernel(const float* __restrict__ s, float* __restrict__ out, int out_size){
    int idx = blockIdx.x * 256 + threadIdx.x;
    if(idx >= out_size) return;
    out[idx] = (idx < BB*LSEQ*HID) ? s[idx] : 64.0f;
}

extern "C" void kernel_launch(void* const* d_in, const int* in_sizes, int n_in,
                              void* d_out, int out_size, void* d_ws, size_t ws_size,
                              hipStream_t stream){
    const float* x        = (const float*)d_in[0];
    const float* conv1_w  = (const float*)d_in[1];
    const float* conv1_b  = (const float*)d_in[2];
    const float* gn1_w    = (const float*)d_in[3];
    const float* gn1_b    = (const float*)d_in[4];
    const float* conv2_w  = (const float*)d_in[5];
    const float* conv2_b  = (const float*)d_in[6];
    const float* gn2_w    = (const float*)d_in[7];
    const float* gn2_b    = (const float*)d_in[8];
    const float* ln_w     = (const float*)d_in[9];
    const float* ln_b     = (const float*)d_in[10];
    const float* in_proj  = (const float*)d_in[11];
    const float* c1d_w    = (const float*)d_in[12];
    const float* c1d_b    = (const float*)d_in[13];
    const float* x_proj   = (const float*)d_in[14];
    const float* dt_w     = (const float*)d_in[15];
    const float* dt_b     = (const float*)d_in[16];
    const float* A_log    = (const float*)d_in[17];
    const float* Dvec     = (const float*)d_in[18];
    const float* out_proj = (const float*)d_in[19];

    float* ws = (float*)d_ws;
    float* s      = ws;                       // 4,194,304 f
    u16*   xz_bf  = (u16*)(ws + 4194304);     // 16,777,216 u16 (8,388,608 f)
    float* y1     = ws + 4194304;             // alias: y1 fp32 (stem only)
    u16*   xt     = (u16*)(ws + 12582912);    // 8,652,800 u16 (4,326,400 f)
    u16*   xcv_bf = (u16*)(ws + 16909312);    // 8,388,608 u16 (4,194,304 f)
    float* y2t    = ws + 16909312;            // alias: y2t fp32 (stem only)
    u16*   xln_bf = (u16*)(ws + 21103616);    // 4,194,304 u16 (2,097,152 f)
    float* xdbl   = ws + 23200768;            // 524,288 f (16384 x 32)
    float* aprod  = ws + 23987200;            // 4,194,304 f
    float* hendb  = ws + 28181504;            // 4,194,304 f
    u16*   y_bf   = (u16*)aprod;              // alias: fits in aprod
    float* hinit  = ws + 32375808;            // 4,194,304 f
    float* stats  = ws + 36570112;            // 64 f
    u16*   ipw_bf = (u16*)(ws + 36570176);    // 1,048,576 u16 (524,288 f)
    u16*   opw_bf = ipw_bf + 1048576;         //   524,288 u16 (262,144 f)
    u16*   c2w_bf = opw_bf + 524288;          //   294,912 u16 (147,456 f)
    u16*   dv_bf  = (u16*)(ws + 37635200);    // 8,388,608 u16 (4,194,304 f)
    u16*   wcomb  = (u16*)(ws + 41829504);    // 1,310,720 u16 (655,360 f) -> end 42,484,864 f

    // ---- weight prep ----
    f2bf_kernel<<<4096, 256, 0, stream>>>(in_proj, ipw_bf);
    f2bf_kernel<<<2048, 256, 0, stream>>>(out_proj, opw_bf);
    c2w_prep_kernel<<<1152, 256, 0, stream>>>(conv2_w, c2w_bf);
    wdt_prep_kernel<<<5120, 256, 0, stream>>>(x_proj, dt_w, wcomb);

    // ---- stem ----
    conv1_kernel<<<dim3(128,4), 256, 0, stream>>>(x, conv1_w, conv1_b, y1);
    zero_stats_kernel<<<1, 64, 0, stream>>>(stats);
    gn_stats_kernel<<<512, 256, 0, stream>>>(y1, stats, 16*H1*W1);
    xt_zero_kernel<<<16900, 256, 0, stream>>>((unsigned*)xt);
    gn1_transform_kernel<<<dim3(4,4,512), dim3(32,8), 0, stream>>>(y1, stats, gn1_w, gn1_b, xt);
    conv2gemm_bf16_kernel<<<dim3(128,2), 256, 0, stream>>>(xt, c2w_bf, conv2_b, y2t);
    zero_stats_kernel<<<1, 64, 0, stream>>>(stats);
    gn2t_stats_kernel<<<dim3(64,4), 256, 0, stream>>>(y2t, stats);
    gn2t_apply_ln_kernel<<<16384, 256, 0, stream>>>(y2t, stats, gn2_w, gn2_b,
                                                    ln_w, ln_b, s, xln_bf);

    // ---- 4 mamba layers ----
    for(int layer = 0; layer < NL; ++layer){
        const float* cw  = c1d_w + (long)layer*DIN*4;
        const float* cb  = c1d_b + (long)layer*DIN;
        const float* dpb = dt_b  + (long)layer*DIN;
        const float* Al  = A_log + (long)layer*DIN*DST;
        const float* Dl  = Dvec  + (long)layer*DIN;
        int lnext = (layer + 1) & 3;   // ln params for the NEXT layer's input

        gemm_bf16_kernel<<<dim3(128,8), 256, 0, stream>>>(
            xln_bf, ipw_bf + (long)layer*1024*256, xz_bf, HID, 2*DIN, 2*DIN, 2);
        conv1d_silu_kernel<<<4096, 256, 0, stream>>>(xz_bf, cw, cb, xcv_bf);
        gemm_dtbc_kernel<<<dim3(128,5), 256, 0, stream>>>(
            xcv_bf, wcomb + (long)layer*640*512, dpb, dv_bf, xdbl);
        scan1_kernel<<<dim3(NCHUNK,2,BB), 256, 0, stream>>>(
            xcv_bf, dv_bf, xdbl, Al, aprod, hendb);
        scan2_kernel<<<128, 256, 0, stream>>>(aprod, hendb, hinit);
        scan3_kernel<<<dim3(NCHUNK,2,BB), 256, 0, stream>>>(
            xcv_bf, dv_bf, xdbl, Al, hinit, Dl, xz_bf, y_bf);
        gemm_out_ln_kernel<<<256, 256, 0, stream>>>(
            y_bf, opw_bf + (long)layer*256*512, s, xln_bf,
            ln_w + lnext*HID, ln_b + lnext*HID);
    }

    copyout_kernel<<<(out_size + 255)/256, 256, 0, stream>>>(s, (float*)d_out, out_size);
}